// Round 1
// baseline (4315.411 us; speedup 1.0000x reference)
//
#include <hip/hip_runtime.h>
#include <math.h>

// ---------------------------------------------------------------------------
// Model constants
// ---------------------------------------------------------------------------
namespace {
constexpr int B_ = 4, T_ = 12, N_ = 2000, D_ = 16, FF_ = 64, E_ = 4, L_ = 2;
constexpr int EA_ = 3000, H_ = 3, HD_ = EA_ / H_;   // 1000
constexpr int BT_ = B_ * T_;                         // 48 rows per r-group
constexpr int R3_ = 3 * BT_;                         // 144 stacked rows
constexpr long long NN_ = (long long)N_ * N_;        // 4,000,000
constexpr int BTN_ = B_ * T_ * N_;                   // 96,000
constexpr float BETA_ = 0.01f, CW_ = 0.001f;

// ---------------------------------------------------------------------------
// Workspace layout (float offsets)
// ---------------------------------------------------------------------------
constexpr size_t OFF_OUT4 = 0;                                   // [B,T,N,D]
constexpr size_t OFF_LOWT = OFF_OUT4 + (size_t)BTN_ * D_;        // lowT^T [N][48]
constexpr size_t OFF_HVT  = OFF_LOWT + BTN_;                     // highV^T [N][48]
constexpr size_t OFF_ALIN = OFF_HVT + BTN_;                      // r^T [N][144]
constexpr size_t OFF_RT   = OFF_ALIN + (size_t)N_ * R3_;         // R^T [EA][144]
constexpr size_t OFF_P    = OFF_RT + (size_t)EA_ * R3_;          // P [144][9000]
constexpr size_t OFF_AOT  = OFF_P + (size_t)R3_ * 3 * EA_;       // Ao^T [EA][144]
constexpr size_t OFF_OT   = OFF_AOT + (size_t)EA_ * R3_;         // O^T  [EA][144]
constexpr size_t OFF_O2P  = OFF_OT + (size_t)EA_ * R3_;          // out2 pre-p2 [B][T*N]
constexpr size_t OFF_OUTP = OFF_O2P + BTN_;                      // outp [B,T,N]
constexpr size_t OFF_O2F  = OFF_OUTP + BTN_;                     // out2 final [B,T,N]
constexpr size_t OFF_G1   = OFF_O2F + BTN_;                      // f1 normalized*10 [8000][12]
constexpr size_t OFF_G2   = OFF_G1 + 96000;                      // f2 normalized [8000][12]
constexpr size_t OFF_LI   = OFF_G2 + 96000;                      // li [8000]
constexpr size_t OFF_S    = OFF_LI + 8000;                       // G row sums [2000]
constexpr size_t OFF_RSL  = OFF_S + 2000;                        // rowsum lowT [48]
constexpr size_t OFF_RSH  = OFF_RSL + 48;                        // rowsum hv [48]
constexpr size_t OFF_STP  = OFF_RSH + 48;                        // stat partials 3*512*2
constexpr size_t OFF_STAT = OFF_STP + 3072;                      // {mu,isd} x3
constexpr size_t OFF_MMP  = OFF_STAT + 8;                        // minmax partials [3][64][2]
constexpr size_t OFF_AB   = OFF_MMP + 384;                       // {alpha,beta} x3
constexpr size_t OFF_CSP  = OFF_AB + 8;                          // colsum partials [16][3000]
constexpr size_t OFF_CS   = OFF_CSP + 48000;                     // lt_w colsums [3000]
constexpr size_t OFF_FEAT = OFF_CS + 3000;                       // feat [B][D]
constexpr size_t OFF_GATE = OFF_FEAT + 64;                       // gates [B][E]
constexpr size_t OFF_BAL  = OFF_GATE + 16;                       // balance scalar
constexpr size_t OFF_PART = ((OFF_BAL + 1 + 255) & ~(size_t)255); // GEMM split-K partials
} // namespace

// ---------------------------------------------------------------------------
// Small helpers
// ---------------------------------------------------------------------------
__device__ __forceinline__ float waveReduceSum(float v) {
  for (int off = 32; off; off >>= 1) v += __shfl_down(v, off);
  return v;
}

// ---------------------------------------------------------------------------
__global__ void k_init(float* ws) {
  if (threadIdx.x == 0) ws[OFF_BAL] = 0.f;
}

// out4[b,t,n,d] = x[b,t,n]*sw[d] + sb[d]
__global__ void k_start(const float* __restrict__ x, const float* __restrict__ sw,
                        const float* __restrict__ sb, float* __restrict__ out4) {
  int i = blockIdx.x * 256 + threadIdx.x;
  if (i >= BTN_ * D_) return;
  int d = i & 15;
  out4[i] = fmaf(x[i >> 4], sw[d], sb[d]);
}

// feat[b,d] = mean over (t,n) of out4
__global__ void k_feat(const float* __restrict__ out4, float* __restrict__ feat) {
  int b = blockIdx.x >> 4, d = blockIdx.x & 15;
  float s = 0.f;
  for (int tn = threadIdx.x; tn < T_ * N_; tn += 256)
    s += out4[((size_t)b * T_ * N_ + tn) * D_ + d];
  __shared__ float red[4];
  s = waveReduceSum(s);
  if ((threadIdx.x & 63) == 0) red[threadIdx.x >> 6] = s;
  __syncthreads();
  if (threadIdx.x == 0)
    feat[blockIdx.x] = (red[0] + red[1] + red[2] + red[3]) * (1.f / (T_ * N_));
}

// logits -> top2 -> gates + balance accumulation (single block)
__global__ void k_gate(const float* __restrict__ feat, const float* __restrict__ gw,
                       float* __restrict__ ws, int l) {
  __shared__ float lg[B_ * E_];
  int tid = threadIdx.x;
  if (tid < B_ * E_) {
    int b = tid >> 2, e = tid & 3;
    float s = 0.f;
    for (int d = 0; d < D_; ++d) s = fmaf(feat[b * D_ + d], gw[(l * D_ + d) * E_ + e], s);
    lg[tid] = s;
  }
  __syncthreads();
  if (tid == 0) {
    float* gates = ws + OFF_GATE;
    float imp[E_] = {0, 0, 0, 0}, load[E_] = {0, 0, 0, 0};
    for (int i = 0; i < B_ * E_; ++i) gates[i] = 0.f;
    for (int b = 0; b < B_; ++b) {
      const float* lb = lg + b * E_;
      int i1 = 0; float v1 = lb[0];
      for (int e = 1; e < E_; ++e) if (lb[e] > v1) { v1 = lb[e]; i1 = e; }
      int i2 = -1; float v2 = -1e30f;
      for (int e = 0; e < E_; ++e) { if (e == i1) continue; if (lb[e] > v2) { v2 = lb[e]; i2 = e; } }
      float e2 = expf(v2 - v1);
      float den = 1.f + e2;
      float g1 = 1.f / den, g2 = e2 / den;
      gates[b * E_ + i1] = g1; gates[b * E_ + i2] = g2;
      imp[i1] += g1; imp[i2] += g2; load[i1] += 1.f; load[i2] += 1.f;
    }
    float bal = 0.f;
    float m = 0.f; for (int e = 0; e < E_; ++e) m += imp[e]; m *= 0.25f;
    float v = 0.f; for (int e = 0; e < E_; ++e) { float d = imp[e] - m; v += d * d; } v *= 0.25f;
    bal += v / (m * m + 1e-10f);
    m = 0.f; for (int e = 0; e < E_; ++e) m += load[e]; m *= 0.25f;
    v = 0.f; for (int e = 0; e < E_; ++e) { float d = load[e] - m; v += d * d; } v *= 0.25f;
    bal += v / (m * m + 1e-10f);
    ws[OFF_BAL] += bal;
  }
}

// MoE expert apply (in-place residual), layer l
__global__ void k_expert(float* __restrict__ out4, const float* __restrict__ w1,
                         const float* __restrict__ b1, const float* __restrict__ w2,
                         const float* __restrict__ b2, const float* __restrict__ ws, int l) {
  int b = blockIdx.y;
  int tn = blockIdx.x * 256 + threadIdx.x;
  if (tn >= T_ * N_) return;
  float* row = out4 + ((size_t)b * T_ * N_ + tn) * D_;
  float r[D_], acc[D_];
#pragma unroll
  for (int d = 0; d < D_; ++d) { r[d] = row[d]; acc[d] = r[d]; }
  const float* gates = ws + OFF_GATE;
  for (int e = 0; e < E_; ++e) {
    float g = gates[b * E_ + e];
    if (g <= 0.f) continue;
    const float* W1 = w1 + (size_t)(l * E_ + e) * D_ * FF_;
    const float* B1 = b1 + (size_t)(l * E_ + e) * FF_;
    const float* W2 = w2 + (size_t)(l * E_ + e) * FF_ * D_;
    const float* B2 = b2 + (size_t)(l * E_ + e) * D_;
#pragma unroll 4
    for (int f = 0; f < FF_; ++f) {
      float p = B1[f];
#pragma unroll
      for (int d = 0; d < D_; ++d) p = fmaf(r[d], W1[d * FF_ + f], p);
      float c = 0.7978845608028654f * (p + 0.044715f * p * p * p);
      float hv = 0.5f * p * (1.f + tanhf(c));
      float gh = g * hv;
#pragma unroll
      for (int d = 0; d < D_; ++d) acc[d] = fmaf(gh, W2[f * D_ + d], acc[d]);
    }
#pragma unroll
    for (int d = 0; d < D_; ++d) acc[d] = fmaf(g, B2[d], acc[d]);
  }
#pragma unroll
  for (int d = 0; d < D_; ++d) row[d] = acc[d];
}

// wavelet split; writes transposed [n][row], row = t*B+b
__global__ void k_wavelet(const float* __restrict__ x, const float* __restrict__ velo,
                          float* __restrict__ lowT, float* __restrict__ hvT) {
  int i = blockIdx.x * 256 + threadIdx.x;
  if (i >= BTN_) return;
  int b = i / (T_ * N_);
  int t = (i / N_) % T_;
  int n = i % N_;
  int ip = b * T_ * N_ + ((t + T_ - 1) % T_) * N_ + n;
  int row = t * B_ + b;
  lowT[(size_t)n * BT_ + row] = 0.5f * (x[i] + x[ip]);
  hvT[(size_t)n * BT_ + row] = 0.5f * (velo[i] - velo[ip]);
}

// row sums of lowT / hvT (96 blocks)
__global__ void k_rowsum(const float* __restrict__ lowT, const float* __restrict__ hvT,
                         float* __restrict__ ws) {
  int which = blockIdx.x / BT_;
  int row = blockIdx.x % BT_;
  const float* M = which ? hvT : lowT;
  float s = 0.f;
  for (int n = threadIdx.x; n < N_; n += 256) s += M[(size_t)n * BT_ + row];
  __shared__ float red[4];
  s = waveReduceSum(s);
  if ((threadIdx.x & 63) == 0) red[threadIdx.x >> 6] = s;
  __syncthreads();
  if (threadIdx.x == 0) ws[(which ? OFF_RSH : OFF_RSL) + row] = red[0] + red[1] + red[2] + red[3];
}

// S[m] = sum_n v0[m]/adj[m,n]   (matches JAX G row sums up to order)
__global__ void k_S(const float* __restrict__ adj, const float* __restrict__ v0,
                    float* __restrict__ S) {
  int m = blockIdx.x;
  float vm = v0[m];
  const float* a = adj + (size_t)m * N_;
  float s = 0.f;
  for (int n = threadIdx.x; n < N_; n += 256) s += vm / a[n];
  __shared__ float red[4];
  s = waveReduceSum(s);
  if ((threadIdx.x & 63) == 0) red[threadIdx.x >> 6] = s;
  __syncthreads();
  if (threadIdx.x == 0) S[m] = red[0] + red[1] + red[2] + red[3];
}

// sum / sumsq of a dense NxN matrix  (512 blocks)
__global__ void k_stats(const float* __restrict__ M, float* __restrict__ part) {
  float s = 0.f, ss = 0.f;
  for (long long i = blockIdx.x * 256 + threadIdx.x; i < NN_; i += 512 * 256) {
    float v = M[i];
    s += v; ss = fmaf(v, v, ss);
  }
  __shared__ float r1[4], r2[4];
  for (int off = 32; off; off >>= 1) { s += __shfl_down(s, off); ss += __shfl_down(ss, off); }
  if ((threadIdx.x & 63) == 0) { r1[threadIdx.x >> 6] = s; r2[threadIdx.x >> 6] = ss; }
  __syncthreads();
  if (threadIdx.x == 0) {
    part[blockIdx.x * 2] = r1[0] + r1[1] + r1[2] + r1[3];
    part[blockIdx.x * 2 + 1] = r2[0] + r2[1] + r2[2] + r2[3];
  }
}

// same but for the on-the-fly NS laplacian
__global__ void k_nsstats(const float* __restrict__ adj, const float* __restrict__ v0,
                          const float* __restrict__ S, float* __restrict__ part) {
  float s = 0.f, ss = 0.f;
  for (long long i = blockIdx.x * 256 + threadIdx.x; i < NN_; i += 512 * 256) {
    int m = (int)(i / N_), n = (int)(i % N_);
    float e = -(v0[m] / adj[i]);
    if (m == n) e += S[m];
    s += e; ss = fmaf(e, e, ss);
  }
  __shared__ float r1[4], r2[4];
  for (int off = 32; off; off >>= 1) { s += __shfl_down(s, off); ss += __shfl_down(ss, off); }
  if ((threadIdx.x & 63) == 0) { r1[threadIdx.x >> 6] = s; r2[threadIdx.x >> 6] = ss; }
  __syncthreads();
  if (threadIdx.x == 0) {
    part[blockIdx.x * 2] = r1[0] + r1[1] + r1[2] + r1[3];
    part[blockIdx.x * 2 + 1] = r2[0] + r2[1] + r2[2] + r2[3];
  }
}

// combine 512 {sum,sumsq} partials -> {mu, 1/std}
__global__ void k_stats2(const float* __restrict__ part, float* __restrict__ stat) {
  float s = 0.f, ss = 0.f;
  for (int i = threadIdx.x; i < 512; i += 256) { s += part[i * 2]; ss += part[i * 2 + 1]; }
  __shared__ float r1[4], r2[4];
  for (int off = 32; off; off >>= 1) { s += __shfl_down(s, off); ss += __shfl_down(ss, off); }
  if ((threadIdx.x & 63) == 0) { r1[threadIdx.x >> 6] = s; r2[threadIdx.x >> 6] = ss; }
  __syncthreads();
  if (threadIdx.x == 0) {
    float su = r1[0] + r1[1] + r1[2] + r1[3];
    float sq = r2[0] + r2[1] + r2[2] + r2[3];
    float mu = su * (1.f / (float)NN_);
    float var = sq * (1.f / (float)NN_) - mu * mu;
    stat[0] = mu;
    stat[1] = 1.f / sqrtf(var);
  }
}

// ---------------------------------------------------------------------------
// Skinny streaming GEMM: part[ks][ROWS][NC] += A^T[K][ROWS] x B[K][NC] (chunk ks)
// ---------------------------------------------------------------------------
template <int ROWS>
__global__ void k_gemmAT(const float* __restrict__ AT, const float* __restrict__ Bm,
                         float* __restrict__ part, int Kdim, int NC, int kchunk) {
  int col = blockIdx.x * 256 + threadIdx.x;
  int m0 = blockIdx.y * kchunk;
  int m1 = min(Kdim, m0 + kchunk);
  float acc[ROWS];
#pragma unroll
  for (int r = 0; r < ROWS; ++r) acc[r] = 0.f;
  if (col < NC) {
    const float* bp = Bm + (size_t)m0 * NC + col;
    const float* ap = AT + (size_t)m0 * ROWS;
    for (int m = m0; m < m1; ++m, bp += NC, ap += ROWS) {
      float bv = *bp;
#pragma unroll
      for (int r = 0; r < ROWS; ++r) acc[r] = fmaf(ap[r], bv, acc[r]);
    }
    float* pp = part + (size_t)blockIdx.y * ROWS * NC + col;
#pragma unroll
    for (int r = 0; r < ROWS; ++r) pp[(size_t)r * NC] = acc[r];
  }
}

// NS-laplacian variant: B generated on the fly from adj/v0/S
__global__ void k_gemmNS(const float* __restrict__ hvT, const float* __restrict__ adj,
                         const float* __restrict__ v0, const float* __restrict__ S,
                         float* __restrict__ part, int kchunk) {
  int col = blockIdx.x * 256 + threadIdx.x;
  int m0 = blockIdx.y * kchunk;
  int m1 = min(N_, m0 + kchunk);
  float acc[BT_];
#pragma unroll
  for (int r = 0; r < BT_; ++r) acc[r] = 0.f;
  if (col < N_) {
    for (int m = m0; m < m1; ++m) {
      float bv = -(v0[m] / adj[(size_t)m * N_ + col]);
      if (m == col) bv += S[m];
      const float* ap = hvT + (size_t)m * BT_;
#pragma unroll
      for (int r = 0; r < BT_; ++r) acc[r] = fmaf(ap[r], bv, acc[r]);
    }
    float* pp = part + (size_t)blockIdx.y * BT_ * N_ + col;
#pragma unroll
    for (int r = 0; r < BT_; ++r) pp[(size_t)r * N_] = acc[r];
  }
}

// epilogue: r matmul + fused std-normalization -> ALIN[n][g*48+row]
__global__ void k_epiR(const float* __restrict__ part, float* __restrict__ ws,
                       int ksplit, int g, int statIdx, size_t rsOff) {
  int n = blockIdx.x * 256 + threadIdx.x;
  int row = blockIdx.y;
  if (n >= N_) return;
  float s = 0.f;
  for (int ks = 0; ks < ksplit; ++ks) s += part[((size_t)(ks * BT_ + row)) * N_ + n];
  float mu = ws[OFF_STAT + statIdx], isd = ws[OFF_STAT + statIdx + 1];
  float val = (s - mu * ws[rsOff + row]) * isd;
  ws[OFF_ALIN + (size_t)n * R3_ + g * BT_ + row] = val;
}

// min/max per r-group
__global__ void k_minmax(const float* __restrict__ alin, float* __restrict__ mmp) {
  int g = blockIdx.y;
  float mn = 3.4e38f, mx = -3.4e38f;
  for (int i = blockIdx.x * 256 + threadIdx.x; i < N_ * BT_; i += 64 * 256) {
    int n = i / BT_, r = i % BT_;
    float v = alin[(size_t)n * R3_ + g * BT_ + r];
    mn = fminf(mn, v); mx = fmaxf(mx, v);
  }
  __shared__ float rn[4], rx[4];
  for (int off = 32; off; off >>= 1) {
    mn = fminf(mn, __shfl_down(mn, off));
    mx = fmaxf(mx, __shfl_down(mx, off));
  }
  if ((threadIdx.x & 63) == 0) { rn[threadIdx.x >> 6] = mn; rx[threadIdx.x >> 6] = mx; }
  __syncthreads();
  if (threadIdx.x == 0) {
    mn = fminf(fminf(rn[0], rn[1]), fminf(rn[2], rn[3]));
    mx = fmaxf(fmaxf(rx[0], rx[1]), fmaxf(rx[2], rx[3]));
    mmp[(size_t)(g * 64 + blockIdx.x) * 2] = mn;
    mmp[(size_t)(g * 64 + blockIdx.x) * 2 + 1] = mx;
  }
}

__global__ void k_minmax2(float* __restrict__ ws) {
  int g = blockIdx.x;
  int i = threadIdx.x;  // 64 threads
  float mn = ws[OFF_MMP + (size_t)(g * 64 + i) * 2];
  float mx = ws[OFF_MMP + (size_t)(g * 64 + i) * 2 + 1];
  for (int off = 32; off; off >>= 1) {
    mn = fminf(mn, __shfl_down(mn, off));
    mx = fmaxf(mx, __shfl_down(mx, off));
  }
  if (i == 0) {
    float denom = fmaxf(mx - mn, 1e-8f);
    float a = 1.f / denom;
    ws[OFF_AB + g * 2] = a;
    ws[OFF_AB + g * 2 + 1] = -mn * a;
  }
}

// lt_w column sums (two stage)
__global__ void k_colsum(const float* __restrict__ ltw, float* __restrict__ csp) {
  int e = blockIdx.x * 256 + threadIdx.x;
  int ks = blockIdx.y;
  if (e >= EA_) return;
  float s = 0.f;
  for (int n = ks * 125; n < (ks + 1) * 125; ++n) s += ltw[(size_t)n * EA_ + e];
  csp[(size_t)ks * EA_ + e] = s;
}
__global__ void k_colsum2(float* __restrict__ ws) {
  int e = blockIdx.x * 256 + threadIdx.x;
  if (e >= EA_) return;
  float s = 0.f;
  for (int ks = 0; ks < 16; ++ks) s += ws[OFF_CSP + (size_t)ks * EA_ + e];
  ws[OFF_CS + e] = s;
}

// lin epilogue: rng01 folded in -> RT[e][row144]
__global__ void k_epiLin(const float* __restrict__ part, const float* __restrict__ ltb,
                         float* __restrict__ ws, int ksplit) {
  int e = blockIdx.x * 256 + threadIdx.x;
  int row = blockIdx.y;
  if (e >= EA_) return;
  float s = 0.f;
  for (int ks = 0; ks < ksplit; ++ks) s += part[((size_t)(ks * R3_ + row)) * EA_ + e];
  int g = row / BT_;
  float a = ws[OFF_AB + g * 2], bb = ws[OFF_AB + g * 2 + 1];
  ws[OFF_RT + (size_t)e * R3_ + row] = fmaf(a, s, fmaf(bb, ws[OFF_CS + e], ltb[e]));
}

// qkv epilogue -> P[row144][9000]
__global__ void k_epiQkv(const float* __restrict__ part, const float* __restrict__ qkvb,
                         float* __restrict__ P, int ksplit) {
  int c = blockIdx.x * 256 + threadIdx.x;
  int row = blockIdx.y;
  if (c >= 3 * EA_) return;
  float s = 0.f;
  for (int ks = 0; ks < ksplit; ++ks) s += part[((size_t)(ks * R3_ + row)) * (3 * EA_) + c];
  P[(size_t)row * (3 * EA_) + c] = s + qkvb[c];
}

// attention core (tiny): one block per (mha, s, b, h)
__global__ void k_attn(const float* __restrict__ P, float* __restrict__ AoT) {
  int mha = blockIdx.y;
  int s_ = blockIdx.x / (B_ * H_);
  int rem = blockIdx.x % (B_ * H_);
  int b = rem / H_, h = rem % H_;
  const int pq[3] = {0, 1, 2}, pk[3] = {1, 2, 0}, pv[3] = {2, 0, 1};
  const float* qrow = P + ((size_t)(pq[mha] * BT_ + s_ * B_ + b)) * (3 * EA_) + h * HD_;
  __shared__ float sc[T_];
  __shared__ float red[4];
  for (int t = 0; t < T_; ++t) {
    const float* krow = P + ((size_t)(pk[mha] * BT_ + t * B_ + b)) * (3 * EA_) + EA_ + h * HD_;
    float p = 0.f;
    for (int d = threadIdx.x; d < HD_; d += 256) p = fmaf(qrow[d], krow[d], p);
    p = waveReduceSum(p);
    if ((threadIdx.x & 63) == 0) red[threadIdx.x >> 6] = p;
    __syncthreads();
    if (threadIdx.x == 0) sc[t] = (red[0] + red[1] + red[2] + red[3]) * 0.031622776601683794f;
    __syncthreads();
  }
  float a[T_];
  float m = sc[0];
#pragma unroll
  for (int t = 1; t < T_; ++t) m = fmaxf(m, sc[t]);
  float sum = 0.f;
#pragma unroll
  for (int t = 0; t < T_; ++t) { a[t] = expf(sc[t] - m); sum += a[t]; }
  float inv = 1.f / sum;
#pragma unroll
  for (int t = 0; t < T_; ++t) a[t] *= inv;
  int orow = mha * BT_ + s_ * B_ + b;
  for (int d = threadIdx.x; d < HD_; d += 256) {
    float o = 0.f;
#pragma unroll
    for (int t = 0; t < T_; ++t)
      o = fmaf(a[t], P[((size_t)(pv[mha] * BT_ + t * B_ + b)) * (3 * EA_) + 2 * EA_ + h * HD_ + d], o);
    AoT[(size_t)(h * HD_ + d) * R3_ + orow] = o;
  }
}

// attn-out epilogue -> OT[c][row144]
__global__ void k_epiAO(const float* __restrict__ part, const float* __restrict__ aob,
                        float* __restrict__ OT, int ksplit) {
  int c = blockIdx.x * 256 + threadIdx.x;
  int row = blockIdx.y;
  if (c >= EA_) return;
  float s = 0.f;
  for (int ks = 0; ks < ksplit; ++ks) s += part[((size_t)(ks * R3_ + row)) * EA_ + c];
  OT[(size_t)c * R3_ + row] = s + aob[c];
}

// ll epilogue: sum three mha branches -> out2_pre[b][t*N+n] (with BETA and 3*bias)
__global__ void k_epiLL(const float* __restrict__ part, const float* __restrict__ llb,
                        float* __restrict__ o2p, int ksplit) {
  int n = blockIdx.x * 256 + threadIdx.x;
  int row = blockIdx.y;  // t*B+b
  if (n >= N_) return;
  float s = 0.f;
  for (int g = 0; g < 3; ++g)
    for (int ks = 0; ks < ksplit; ++ks)
      s += part[((size_t)(ks * R3_ + g * BT_ + row)) * N_ + n];
  int t = row / B_, b = row % B_;
  o2p[(size_t)b * (T_ * N_) + t * N_ + n] = BETA_ * (s + 3.f * llb[n]);
}

// trunk projection outp[b,t,n]
__global__ void k_proj(const float* __restrict__ out4, const float* __restrict__ pw,
                       const float* __restrict__ pb, float* __restrict__ outp) {
  int i = blockIdx.x * 256 + threadIdx.x;
  if (i >= BTN_) return;
  int b = i / (T_ * N_);
  int t = (i / N_) % T_;
  int n = i % N_;
  float acc = pb[t];
  for (int t2 = 0; t2 < T_; ++t2) {
    const float* o = out4 + ((size_t)(b * T_ + t2) * N_ + n) * D_;
#pragma unroll
    for (int d = 0; d < D_; ++d) acc = fmaf(o[d], pw[(t2 * D_ + d) * T_ + t], acc);
  }
  outp[i] = acc;
}

// p2 (replicates the reshape(-1,T) quirk exactly)
__global__ void k_p2(const float* __restrict__ o2p, const float* __restrict__ p2w,
                     const float* __restrict__ p2b, float* __restrict__ o2f) {
  int i = blockIdx.x * 256 + threadIdx.x;
  if (i >= BTN_) return;
  int b = i / (T_ * N_);
  int t = (i / N_) % T_;
  int n = i % N_;
  float acc = p2b[t];
  const float* src = o2p + (size_t)b * (T_ * N_) + (size_t)n * T_;
#pragma unroll
  for (int c = 0; c < T_; ++c) acc = fmaf(src[c], p2w[c * T_ + t], acc);
  o2f[i] = acc;
}

__global__ void k_out3(const float* __restrict__ outp, const float* __restrict__ o2f,
                       float* __restrict__ dout) {
  int i = blockIdx.x * 256 + threadIdx.x;
  if (i < BTN_) dout[i] = outp[i] + o2f[i];
}

// row-normalize f1 (x10 for /0.1) and f2
__global__ void k_fnorm(const float* __restrict__ outp, const float* __restrict__ o2f,
                        float* __restrict__ g1, float* __restrict__ g2) {
  int r = blockIdx.x * 256 + threadIdx.x;
  if (r >= B_ * N_) return;
  int b = r / N_, n = r % N_;
  float v1[T_], v2[T_];
  float s1 = 0.f, s2 = 0.f;
#pragma unroll
  for (int t = 0; t < T_; ++t) {
    v1[t] = outp[(size_t)b * T_ * N_ + t * N_ + n];
    v2[t] = o2f[(size_t)b * T_ * N_ + t * N_ + n];
    s1 = fmaf(v1[t], v1[t], s1);
    s2 = fmaf(v2[t], v2[t], s2);
  }
  float n1 = fmaxf(sqrtf(s1), 1e-12f), n2 = fmaxf(sqrtf(s2), 1e-12f);
  float i1 = 10.f / n1, i2 = 1.f / n2;
#pragma unroll
  for (int t = 0; t < T_; ++t) {
    g1[(size_t)r * T_ + t] = v1[t] * i1;
    g2[(size_t)r * T_ + t] = v2[t] * i2;
  }
}

// per-row logsumexp + diagonal of sim (16 rows per block)
__global__ void k_lse(const float* __restrict__ g1, const float* __restrict__ g2,
                      float* __restrict__ li) {
  constexpr int TI = 16;
  int i0 = blockIdx.x * TI;
  __shared__ float q[TI][T_];
  __shared__ float sdiag[TI];
  if (threadIdx.x < TI * T_)
    q[threadIdx.x / T_][threadIdx.x % T_] = g1[(size_t)i0 * T_ + threadIdx.x];
  __syncthreads();
  float sm[TI];
#pragma unroll
  for (int ii = 0; ii < TI; ++ii) sm[ii] = 0.f;
  for (int j = threadIdx.x; j < B_ * N_; j += 256) {
    const float4* p = (const float4*)(g2 + (size_t)j * T_);
    float4 A = p[0], Bv = p[1], C = p[2];
    float v[T_] = {A.x, A.y, A.z, A.w, Bv.x, Bv.y, Bv.z, Bv.w, C.x, C.y, C.z, C.w};
#pragma unroll
    for (int ii = 0; ii < TI; ++ii) {
      float s = 0.f;
#pragma unroll
      for (int t = 0; t < T_; ++t) s = fmaf(q[ii][t], v[t], s);
      sm[ii] += __expf(s);
      if (j == i0 + ii) sdiag[ii] = s;
    }
  }
  __syncthreads();
  __shared__ float red[256];
  for (int ii = 0; ii < TI; ++ii) {
    red[threadIdx.x] = sm[ii];
    __syncthreads();
    for (int st = 128; st; st >>= 1) {
      if (threadIdx.x < st) red[threadIdx.x] += red[threadIdx.x + st];
      __syncthreads();
    }
    if (threadIdx.x == 0) li[i0 + ii] = sdiag[ii] - logf(red[0]);
    __syncthreads();
  }
}

__global__ void k_final(const float* __restrict__ li, const float* __restrict__ ws,
                        float* __restrict__ dout) {
  float s = 0.f;
  for (int i = threadIdx.x; i < B_ * N_; i += 256) s += li[i];
  __shared__ float red[4];
  s = waveReduceSum(s);
  if ((threadIdx.x & 63) == 0) red[threadIdx.x >> 6] = s;
  __syncthreads();
  if (threadIdx.x == 0) {
    float closs = -(red[0] + red[1] + red[2] + red[3]) * (1.f / (B_ * N_));
    dout[BTN_] = ws[OFF_BAL];
    dout[BTN_ + 1] = CW_ * closs;
  }
}

// ---------------------------------------------------------------------------
extern "C" void kernel_launch(void* const* d_in, const int* in_sizes, int n_in,
                              void* d_out, int out_size, void* d_ws, size_t ws_size,
                              hipStream_t stream) {
  const float* x    = (const float*)d_in[0];
  const float* velo = (const float*)d_in[1];
  const float* adj  = (const float*)d_in[2];
  const float* lapd = (const float*)d_in[3];
  const float* laph = (const float*)d_in[4];
  const float* sw   = (const float*)d_in[5];
  const float* sb   = (const float*)d_in[6];
  const float* gw   = (const float*)d_in[7];
  const float* ew1  = (const float*)d_in[8];
  const float* eb1  = (const float*)d_in[9];
  const float* ew2  = (const float*)d_in[10];
  const float* eb2  = (const float*)d_in[11];
  const float* pw   = (const float*)d_in[12];
  const float* pb   = (const float*)d_in[13];
  const float* ltw  = (const float*)d_in[14];
  const float* ltb  = (const float*)d_in[15];
  const float* qkvw = (const float*)d_in[16];
  const float* qkvb = (const float*)d_in[17];
  const float* aow  = (const float*)d_in[18];
  const float* aob  = (const float*)d_in[19];
  const float* llw  = (const float*)d_in[20];
  const float* llb  = (const float*)d_in[21];
  const float* p2w  = (const float*)d_in[22];
  const float* p2b  = (const float*)d_in[23];
  float* ws = (float*)d_ws;
  float* dout = (float*)d_out;
  const float* v0 = velo;  // velo[0,0,:]
  float* part = ws + OFF_PART;
  dim3 b256(256);

  k_init<<<dim3(1), dim3(64), 0, stream>>>(ws);
  k_start<<<dim3((BTN_ * D_ + 255) / 256), b256, 0, stream>>>(x, sw, sb, ws + OFF_OUT4);

  for (int l = 0; l < L_; ++l) {
    k_feat<<<dim3(B_ * D_), b256, 0, stream>>>(ws + OFF_OUT4, ws + OFF_FEAT);
    k_gate<<<dim3(1), dim3(64), 0, stream>>>(ws + OFF_FEAT, gw, ws, l);
    k_expert<<<dim3((T_ * N_ + 255) / 256, B_), b256, 0, stream>>>(ws + OFF_OUT4, ew1, eb1, ew2, eb2, ws, l);
  }

  k_wavelet<<<dim3((BTN_ + 255) / 256), b256, 0, stream>>>(x, velo, ws + OFF_LOWT, ws + OFF_HVT);
  k_rowsum<<<dim3(2 * BT_), b256, 0, stream>>>(ws + OFF_LOWT, ws + OFF_HVT, ws);
  k_S<<<dim3(N_), b256, 0, stream>>>(adj, v0, ws + OFF_S);
  k_stats<<<dim3(512), b256, 0, stream>>>(lapd, ws + OFF_STP);
  k_stats2<<<dim3(1), b256, 0, stream>>>(ws + OFF_STP, ws + OFF_STAT);
  k_stats<<<dim3(512), b256, 0, stream>>>(laph, ws + OFF_STP + 1024);
  k_stats2<<<dim3(1), b256, 0, stream>>>(ws + OFF_STP + 1024, ws + OFF_STAT + 2);
  k_nsstats<<<dim3(512), b256, 0, stream>>>(adj, v0, ws + OFF_S, ws + OFF_STP + 2048);
  k_stats2<<<dim3(1), b256, 0, stream>>>(ws + OFF_STP + 2048, ws + OFF_STAT + 4);

  // r1 / r2 / r3 with fused normalization
  k_gemmAT<48><<<dim3(8, 16), b256, 0, stream>>>(ws + OFF_LOWT, lapd, part, N_, N_, 125);
  k_epiR<<<dim3(8, 48), b256, 0, stream>>>(part, ws, 16, 0, 0, OFF_RSL);
  k_gemmNS<<<dim3(8, 16), b256, 0, stream>>>(ws + OFF_HVT, adj, v0, ws + OFF_S, part, 125);
  k_epiR<<<dim3(8, 48), b256, 0, stream>>>(part, ws, 16, 1, 4, OFF_RSH);
  k_gemmAT<48><<<dim3(8, 16), b256, 0, stream>>>(ws + OFF_LOWT, laph, part, N_, N_, 125);
  k_epiR<<<dim3(8, 48), b256, 0, stream>>>(part, ws, 16, 2, 2, OFF_RSL);

  k_minmax<<<dim3(64, 3), b256, 0, stream>>>(ws + OFF_ALIN, ws + OFF_MMP);
  k_minmax2<<<dim3(3), dim3(64), 0, stream>>>(ws);
  k_colsum<<<dim3(12, 16), b256, 0, stream>>>(ltw, ws + OFF_CSP);
  k_colsum2<<<dim3(12), b256, 0, stream>>>(ws);

  // lin: [144,2000] @ lt_w
  k_gemmAT<144><<<dim3(12, 16), b256, 0, stream>>>(ws + OFF_ALIN, ltw, part, N_, EA_, 125);
  k_epiLin<<<dim3(12, 144), b256, 0, stream>>>(part, ltb, ws, 16);

  // qkv: [144,3000] @ qkv_w[3000,9000]
  int qks = (ws_size >= (OFF_PART + (size_t)8 * R3_ * 3 * EA_) * 4) ? 8 : 4;
  k_gemmAT<144><<<dim3(36, qks), b256, 0, stream>>>(ws + OFF_RT, qkvw, part, EA_, 3 * EA_, (EA_ + qks - 1) / qks);
  k_epiQkv<<<dim3(36, 144), b256, 0, stream>>>(part, qkvb, ws + OFF_P, qks);

  // attention (3 mha in grid.y)
  k_attn<<<dim3(T_ * B_ * H_, 3), b256, 0, stream>>>(ws + OFF_P, ws + OFF_AOT);

  // attn out projection
  k_gemmAT<144><<<dim3(12, 16), b256, 0, stream>>>(ws + OFF_AOT, aow, part, EA_, EA_, 188);
  k_epiAO<<<dim3(12, 144), b256, 0, stream>>>(part, aob, ws + OFF_OT, 16);

  // ll (back) projection + branch sum
  k_gemmAT<144><<<dim3(8, 16), b256, 0, stream>>>(ws + OFF_OT, llw, part, EA_, N_, 188);
  k_epiLL<<<dim3(8, 48), b256, 0, stream>>>(part, llb, ws + OFF_O2P, 16);

  k_proj<<<dim3((BTN_ + 255) / 256), b256, 0, stream>>>(ws + OFF_OUT4, pw, pb, ws + OFF_OUTP);
  k_p2<<<dim3((BTN_ + 255) / 256), b256, 0, stream>>>(ws + OFF_O2P, p2w, p2b, ws + OFF_O2F);
  k_out3<<<dim3((BTN_ + 255) / 256), b256, 0, stream>>>(ws + OFF_OUTP, ws + OFF_O2F, dout);

  k_fnorm<<<dim3((B_ * N_ + 255) / 256), b256, 0, stream>>>(ws + OFF_OUTP, ws + OFF_O2F, ws + OFF_G1, ws + OFF_G2);
  k_lse<<<dim3(B_ * N_ / 16), b256, 0, stream>>>(ws + OFF_G1, ws + OFF_G2, ws + OFF_LI);
  k_final<<<dim3(1), b256, 0, stream>>>(ws + OFF_LI, ws, dout);
}

// Round 2
// 1424.118 us; speedup vs baseline: 3.0302x; 3.0302x over previous
//
#include <hip/hip_runtime.h>
#include <math.h>

// ---------------------------------------------------------------------------
// Model constants
// ---------------------------------------------------------------------------
namespace {
constexpr int B_ = 4, T_ = 12, N_ = 2000, D_ = 16, FF_ = 64, E_ = 4, L_ = 2;
constexpr int EA_ = 3000, H_ = 3, HD_ = EA_ / H_;   // 1000
constexpr int BT_ = B_ * T_;                         // 48 rows per r-group
constexpr int R3_ = 3 * BT_;                         // 144 stacked rows
constexpr long long NN_ = (long long)N_ * N_;        // 4,000,000
constexpr int BTN_ = B_ * T_ * N_;                   // 96,000
constexpr float BETA_ = 0.01f, CW_ = 0.001f;

// ---------------------------------------------------------------------------
// Workspace layout (float offsets)
// ---------------------------------------------------------------------------
constexpr size_t OFF_OUT4 = 0;                                   // [B,T,N,D]
constexpr size_t OFF_LOWT = OFF_OUT4 + (size_t)BTN_ * D_;        // lowT^T [N][48]
constexpr size_t OFF_HVT  = OFF_LOWT + BTN_;                     // highV^T [N][48]
constexpr size_t OFF_ALIN = OFF_HVT + BTN_;                      // r^T [N][144]
constexpr size_t OFF_RT   = OFF_ALIN + (size_t)N_ * R3_;         // R^T [EA][144]
constexpr size_t OFF_P    = OFF_RT + (size_t)EA_ * R3_;          // P [144][9000]
constexpr size_t OFF_AOT  = OFF_P + (size_t)R3_ * 3 * EA_;       // Ao^T [EA][144]
constexpr size_t OFF_OT   = OFF_AOT + (size_t)EA_ * R3_;         // O^T  [EA][144]
constexpr size_t OFF_O2P  = OFF_OT + (size_t)EA_ * R3_;          // out2 pre-p2 [B][T*N]
constexpr size_t OFF_OUTP = OFF_O2P + BTN_;                      // outp [B,T,N]
constexpr size_t OFF_O2F  = OFF_OUTP + BTN_;                     // out2 final [B,T,N]
constexpr size_t OFF_G1   = OFF_O2F + BTN_;                      // f1 normalized*10 [8000][12]
constexpr size_t OFF_G2   = OFF_G1 + 96000;                      // f2 normalized [8000][12]
constexpr size_t OFF_LI   = OFF_G2 + 96000;                      // li [8000]
constexpr size_t OFF_S    = OFF_LI + 8000;                       // G row sums [2000]
constexpr size_t OFF_RSL  = OFF_S + 2000;                        // rowsum lowT [48]
constexpr size_t OFF_RSH  = OFF_RSL + 48;                        // rowsum hv [48]
constexpr size_t OFF_STP  = OFF_RSH + 48;                        // stat partials 3*512*2
constexpr size_t OFF_STAT = OFF_STP + 3072;                      // {mu,isd} x3
constexpr size_t OFF_MMP  = OFF_STAT + 8;                        // minmax partials [3][64][2]
constexpr size_t OFF_AB   = OFF_MMP + 384;                       // {alpha,beta} x3
constexpr size_t OFF_CSP  = OFF_AB + 8;                          // colsum partials [16][3000]
constexpr size_t OFF_CS   = OFF_CSP + 48000;                     // lt_w colsums [3000]
constexpr size_t OFF_FEAT = OFF_CS + 3000;                       // feat [B][D]
constexpr size_t OFF_GATE = OFF_FEAT + 64;                       // gates [B][E]
constexpr size_t OFF_BAL  = OFF_GATE + 16;                       // balance scalar
constexpr size_t OFF_PART = ((OFF_BAL + 1 + 255) & ~(size_t)255); // GEMM split-K partials
} // namespace

// ---------------------------------------------------------------------------
// Small helpers
// ---------------------------------------------------------------------------
__device__ __forceinline__ float waveReduceSum(float v) {
  for (int off = 32; off; off >>= 1) v += __shfl_down(v, off);
  return v;
}

// ---------------------------------------------------------------------------
__global__ void k_init(float* ws) {
  if (threadIdx.x == 0) ws[OFF_BAL] = 0.f;
}

// out4[b,t,n,d] = x[b,t,n]*sw[d] + sb[d]
__global__ void k_start(const float* __restrict__ x, const float* __restrict__ sw,
                        const float* __restrict__ sb, float* __restrict__ out4) {
  int i = blockIdx.x * 256 + threadIdx.x;
  if (i >= BTN_ * D_) return;
  int d = i & 15;
  out4[i] = fmaf(x[i >> 4], sw[d], sb[d]);
}

// feat[b,d] = mean over (t,n) of out4
__global__ void k_feat(const float* __restrict__ out4, float* __restrict__ feat) {
  int b = blockIdx.x >> 4, d = blockIdx.x & 15;
  float s = 0.f;
  for (int tn = threadIdx.x; tn < T_ * N_; tn += 256)
    s += out4[((size_t)b * T_ * N_ + tn) * D_ + d];
  __shared__ float red[4];
  s = waveReduceSum(s);
  if ((threadIdx.x & 63) == 0) red[threadIdx.x >> 6] = s;
  __syncthreads();
  if (threadIdx.x == 0)
    feat[blockIdx.x] = (red[0] + red[1] + red[2] + red[3]) * (1.f / (T_ * N_));
}

// logits -> top2 -> gates + balance accumulation (single block)
__global__ void k_gate(const float* __restrict__ feat, const float* __restrict__ gw,
                       float* __restrict__ ws, int l) {
  __shared__ float lg[B_ * E_];
  int tid = threadIdx.x;
  if (tid < B_ * E_) {
    int b = tid >> 2, e = tid & 3;
    float s = 0.f;
    for (int d = 0; d < D_; ++d) s = fmaf(feat[b * D_ + d], gw[(l * D_ + d) * E_ + e], s);
    lg[tid] = s;
  }
  __syncthreads();
  if (tid == 0) {
    float* gates = ws + OFF_GATE;
    float imp[E_] = {0, 0, 0, 0}, load[E_] = {0, 0, 0, 0};
    for (int i = 0; i < B_ * E_; ++i) gates[i] = 0.f;
    for (int b = 0; b < B_; ++b) {
      const float* lb = lg + b * E_;
      int i1 = 0; float v1 = lb[0];
      for (int e = 1; e < E_; ++e) if (lb[e] > v1) { v1 = lb[e]; i1 = e; }
      int i2 = -1; float v2 = -1e30f;
      for (int e = 0; e < E_; ++e) { if (e == i1) continue; if (lb[e] > v2) { v2 = lb[e]; i2 = e; } }
      float e2 = expf(v2 - v1);
      float den = 1.f + e2;
      float g1 = 1.f / den, g2 = e2 / den;
      gates[b * E_ + i1] = g1; gates[b * E_ + i2] = g2;
      imp[i1] += g1; imp[i2] += g2; load[i1] += 1.f; load[i2] += 1.f;
    }
    float bal = 0.f;
    float m = 0.f; for (int e = 0; e < E_; ++e) m += imp[e]; m *= 0.25f;
    float v = 0.f; for (int e = 0; e < E_; ++e) { float d = imp[e] - m; v += d * d; } v *= 0.25f;
    bal += v / (m * m + 1e-10f);
    m = 0.f; for (int e = 0; e < E_; ++e) m += load[e]; m *= 0.25f;
    v = 0.f; for (int e = 0; e < E_; ++e) { float d = load[e] - m; v += d * d; } v *= 0.25f;
    bal += v / (m * m + 1e-10f);
    ws[OFF_BAL] += bal;
  }
}

// MoE expert apply (in-place residual), layer l
__global__ void k_expert(float* __restrict__ out4, const float* __restrict__ w1,
                         const float* __restrict__ b1, const float* __restrict__ w2,
                         const float* __restrict__ b2, const float* __restrict__ ws, int l) {
  int b = blockIdx.y;
  int tn = blockIdx.x * 256 + threadIdx.x;
  if (tn >= T_ * N_) return;
  float* row = out4 + ((size_t)b * T_ * N_ + tn) * D_;
  float r[D_], acc[D_];
#pragma unroll
  for (int d = 0; d < D_; ++d) { r[d] = row[d]; acc[d] = r[d]; }
  const float* gates = ws + OFF_GATE;
  for (int e = 0; e < E_; ++e) {
    float g = gates[b * E_ + e];
    if (g <= 0.f) continue;
    const float* W1 = w1 + (size_t)(l * E_ + e) * D_ * FF_;
    const float* B1 = b1 + (size_t)(l * E_ + e) * FF_;
    const float* W2 = w2 + (size_t)(l * E_ + e) * FF_ * D_;
    const float* B2 = b2 + (size_t)(l * E_ + e) * D_;
#pragma unroll 4
    for (int f = 0; f < FF_; ++f) {
      float p = B1[f];
#pragma unroll
      for (int d = 0; d < D_; ++d) p = fmaf(r[d], W1[d * FF_ + f], p);
      float c = 0.7978845608028654f * (p + 0.044715f * p * p * p);
      float hv = 0.5f * p * (1.f + tanhf(c));
      float gh = g * hv;
#pragma unroll
      for (int d = 0; d < D_; ++d) acc[d] = fmaf(gh, W2[f * D_ + d], acc[d]);
    }
#pragma unroll
    for (int d = 0; d < D_; ++d) acc[d] = fmaf(g, B2[d], acc[d]);
  }
#pragma unroll
  for (int d = 0; d < D_; ++d) row[d] = acc[d];
}

// wavelet split; writes transposed [n][row], row = t*B+b
__global__ void k_wavelet(const float* __restrict__ x, const float* __restrict__ velo,
                          float* __restrict__ lowT, float* __restrict__ hvT) {
  int i = blockIdx.x * 256 + threadIdx.x;
  if (i >= BTN_) return;
  int b = i / (T_ * N_);
  int t = (i / N_) % T_;
  int n = i % N_;
  int ip = b * T_ * N_ + ((t + T_ - 1) % T_) * N_ + n;
  int row = t * B_ + b;
  lowT[(size_t)n * BT_ + row] = 0.5f * (x[i] + x[ip]);
  hvT[(size_t)n * BT_ + row] = 0.5f * (velo[i] - velo[ip]);
}

// row sums of lowT / hvT (96 blocks)
__global__ void k_rowsum(const float* __restrict__ lowT, const float* __restrict__ hvT,
                         float* __restrict__ ws) {
  int which = blockIdx.x / BT_;
  int row = blockIdx.x % BT_;
  const float* M = which ? hvT : lowT;
  float s = 0.f;
  for (int n = threadIdx.x; n < N_; n += 256) s += M[(size_t)n * BT_ + row];
  __shared__ float red[4];
  s = waveReduceSum(s);
  if ((threadIdx.x & 63) == 0) red[threadIdx.x >> 6] = s;
  __syncthreads();
  if (threadIdx.x == 0) ws[(which ? OFF_RSH : OFF_RSL) + row] = red[0] + red[1] + red[2] + red[3];
}

// S[m] = sum_n v0[m]/adj[m,n]
__global__ void k_S(const float* __restrict__ adj, const float* __restrict__ v0,
                    float* __restrict__ S) {
  int m = blockIdx.x;
  float vm = v0[m];
  const float* a = adj + (size_t)m * N_;
  float s = 0.f;
  for (int n = threadIdx.x; n < N_; n += 256) s += vm / a[n];
  __shared__ float red[4];
  s = waveReduceSum(s);
  if ((threadIdx.x & 63) == 0) red[threadIdx.x >> 6] = s;
  __syncthreads();
  if (threadIdx.x == 0) S[m] = red[0] + red[1] + red[2] + red[3];
}

// sum / sumsq of a dense NxN matrix  (512 blocks)
__global__ void k_stats(const float* __restrict__ M, float* __restrict__ part) {
  float s = 0.f, ss = 0.f;
  for (long long i = blockIdx.x * 256 + threadIdx.x; i < NN_; i += 512 * 256) {
    float v = M[i];
    s += v; ss = fmaf(v, v, ss);
  }
  __shared__ float r1[4], r2[4];
  for (int off = 32; off; off >>= 1) { s += __shfl_down(s, off); ss += __shfl_down(ss, off); }
  if ((threadIdx.x & 63) == 0) { r1[threadIdx.x >> 6] = s; r2[threadIdx.x >> 6] = ss; }
  __syncthreads();
  if (threadIdx.x == 0) {
    part[blockIdx.x * 2] = r1[0] + r1[1] + r1[2] + r1[3];
    part[blockIdx.x * 2 + 1] = r2[0] + r2[1] + r2[2] + r2[3];
  }
}

// same but for the on-the-fly NS laplacian
__global__ void k_nsstats(const float* __restrict__ adj, const float* __restrict__ v0,
                          const float* __restrict__ S, float* __restrict__ part) {
  float s = 0.f, ss = 0.f;
  for (long long i = blockIdx.x * 256 + threadIdx.x; i < NN_; i += 512 * 256) {
    int m = (int)(i / N_), n = (int)(i % N_);
    float e = -(v0[m] / adj[i]);
    if (m == n) e += S[m];
    s += e; ss = fmaf(e, e, ss);
  }
  __shared__ float r1[4], r2[4];
  for (int off = 32; off; off >>= 1) { s += __shfl_down(s, off); ss += __shfl_down(ss, off); }
  if ((threadIdx.x & 63) == 0) { r1[threadIdx.x >> 6] = s; r2[threadIdx.x >> 6] = ss; }
  __syncthreads();
  if (threadIdx.x == 0) {
    part[blockIdx.x * 2] = r1[0] + r1[1] + r1[2] + r1[3];
    part[blockIdx.x * 2 + 1] = r2[0] + r2[1] + r2[2] + r2[3];
  }
}

// combine 512 {sum,sumsq} partials -> {mu, 1/std}
__global__ void k_stats2(const float* __restrict__ part, float* __restrict__ stat) {
  float s = 0.f, ss = 0.f;
  for (int i = threadIdx.x; i < 512; i += 256) { s += part[i * 2]; ss += part[i * 2 + 1]; }
  __shared__ float r1[4], r2[4];
  for (int off = 32; off; off >>= 1) { s += __shfl_down(s, off); ss += __shfl_down(ss, off); }
  if ((threadIdx.x & 63) == 0) { r1[threadIdx.x >> 6] = s; r2[threadIdx.x >> 6] = ss; }
  __syncthreads();
  if (threadIdx.x == 0) {
    float su = r1[0] + r1[1] + r1[2] + r1[3];
    float sq = r2[0] + r2[1] + r2[2] + r2[3];
    float mu = su * (1.f / (float)NN_);
    float var = sq * (1.f / (float)NN_) - mu * mu;
    stat[0] = mu;
    stat[1] = 1.f / sqrtf(var);
  }
}

// ---------------------------------------------------------------------------
// Skinny streaming GEMM, 48 accumulator rows per block (NEVER more -> no spill).
// Row-groups of a taller A are handled by blockIdx.z: rows [g*48, g*48+48).
// part[(ks*rowTot + g*48 + r)*NC + col] = partial over K-chunk ks.
// ---------------------------------------------------------------------------
__global__ __launch_bounds__(256) void k_gemm48(
    const float* __restrict__ AT, int lda, int rowTot,
    const float* __restrict__ Bm, float* __restrict__ part,
    int Kdim, int NC, int kchunk) {
  int col = blockIdx.x * 256 + threadIdx.x;
  int g = blockIdx.z;
  int m0 = blockIdx.y * kchunk;
  int m1 = min(Kdim, m0 + kchunk);
  float acc[BT_];
#pragma unroll
  for (int r = 0; r < BT_; ++r) acc[r] = 0.f;
  if (col < NC) {
    const float* bp = Bm + (size_t)m0 * NC + col;
    const float* ap = AT + (size_t)m0 * lda + g * BT_;
    for (int m = m0; m < m1; ++m, bp += NC, ap += lda) {
      float bv = *bp;
#pragma unroll
      for (int r = 0; r < BT_; ++r) acc[r] = fmaf(ap[r], bv, acc[r]);
    }
    float* pp = part + ((size_t)blockIdx.y * rowTot + g * BT_) * NC + col;
#pragma unroll
    for (int r = 0; r < BT_; ++r) pp[(size_t)r * NC] = acc[r];
  }
}

// NS-laplacian variant: B generated on the fly from adj/v0/S
__global__ __launch_bounds__(256) void k_gemmNS(
    const float* __restrict__ hvT, const float* __restrict__ adj,
    const float* __restrict__ v0, const float* __restrict__ S,
    float* __restrict__ part, int kchunk) {
  int col = blockIdx.x * 256 + threadIdx.x;
  int m0 = blockIdx.y * kchunk;
  int m1 = min(N_, m0 + kchunk);
  float acc[BT_];
#pragma unroll
  for (int r = 0; r < BT_; ++r) acc[r] = 0.f;
  if (col < N_) {
    for (int m = m0; m < m1; ++m) {
      float bv = -(v0[m] / adj[(size_t)m * N_ + col]);
      if (m == col) bv += S[m];
      const float* ap = hvT + (size_t)m * BT_;
#pragma unroll
      for (int r = 0; r < BT_; ++r) acc[r] = fmaf(ap[r], bv, acc[r]);
    }
    float* pp = part + (size_t)blockIdx.y * BT_ * N_ + col;
#pragma unroll
    for (int r = 0; r < BT_; ++r) pp[(size_t)r * N_] = acc[r];
  }
}

// epilogue: r matmul + fused std-normalization -> ALIN[n][g*48+row]
__global__ void k_epiR(const float* __restrict__ part, float* __restrict__ ws,
                       int ksplit, int g, int statIdx, size_t rsOff) {
  int n = blockIdx.x * 256 + threadIdx.x;
  int row = blockIdx.y;
  if (n >= N_) return;
  float s = 0.f;
  for (int ks = 0; ks < ksplit; ++ks) s += part[((size_t)(ks * BT_ + row)) * N_ + n];
  float mu = ws[OFF_STAT + statIdx], isd = ws[OFF_STAT + statIdx + 1];
  float val = (s - mu * ws[rsOff + row]) * isd;
  ws[OFF_ALIN + (size_t)n * R3_ + g * BT_ + row] = val;
}

// min/max per r-group
__global__ void k_minmax(const float* __restrict__ alin, float* __restrict__ mmp) {
  int g = blockIdx.y;
  float mn = 3.4e38f, mx = -3.4e38f;
  for (int i = blockIdx.x * 256 + threadIdx.x; i < N_ * BT_; i += 64 * 256) {
    int n = i / BT_, r = i % BT_;
    float v = alin[(size_t)n * R3_ + g * BT_ + r];
    mn = fminf(mn, v); mx = fmaxf(mx, v);
  }
  __shared__ float rn[4], rx[4];
  for (int off = 32; off; off >>= 1) {
    mn = fminf(mn, __shfl_down(mn, off));
    mx = fmaxf(mx, __shfl_down(mx, off));
  }
  if ((threadIdx.x & 63) == 0) { rn[threadIdx.x >> 6] = mn; rx[threadIdx.x >> 6] = mx; }
  __syncthreads();
  if (threadIdx.x == 0) {
    mn = fminf(fminf(rn[0], rn[1]), fminf(rn[2], rn[3]));
    mx = fmaxf(fmaxf(rx[0], rx[1]), fmaxf(rx[2], rx[3]));
    mmp[(size_t)(g * 64 + blockIdx.x) * 2] = mn;
    mmp[(size_t)(g * 64 + blockIdx.x) * 2 + 1] = mx;
  }
}

__global__ void k_minmax2(float* __restrict__ ws) {
  int g = blockIdx.x;
  int i = threadIdx.x;  // 64 threads
  float mn = ws[OFF_MMP + (size_t)(g * 64 + i) * 2];
  float mx = ws[OFF_MMP + (size_t)(g * 64 + i) * 2 + 1];
  for (int off = 32; off; off >>= 1) {
    mn = fminf(mn, __shfl_down(mn, off));
    mx = fmaxf(mx, __shfl_down(mx, off));
  }
  if (i == 0) {
    float denom = fmaxf(mx - mn, 1e-8f);
    float a = 1.f / denom;
    ws[OFF_AB + g * 2] = a;
    ws[OFF_AB + g * 2 + 1] = -mn * a;
  }
}

// lt_w column sums (two stage)
__global__ void k_colsum(const float* __restrict__ ltw, float* __restrict__ csp) {
  int e = blockIdx.x * 256 + threadIdx.x;
  int ks = blockIdx.y;
  if (e >= EA_) return;
  float s = 0.f;
  for (int n = ks * 125; n < (ks + 1) * 125; ++n) s += ltw[(size_t)n * EA_ + e];
  csp[(size_t)ks * EA_ + e] = s;
}
__global__ void k_colsum2(float* __restrict__ ws) {
  int e = blockIdx.x * 256 + threadIdx.x;
  if (e >= EA_) return;
  float s = 0.f;
  for (int ks = 0; ks < 16; ++ks) s += ws[OFF_CSP + (size_t)ks * EA_ + e];
  ws[OFF_CS + e] = s;
}

// lin epilogue: rng01 folded in -> RT[e][row144]
__global__ void k_epiLin(const float* __restrict__ part, const float* __restrict__ ltb,
                         float* __restrict__ ws, int ksplit) {
  int e = blockIdx.x * 256 + threadIdx.x;
  int row = blockIdx.y;
  if (e >= EA_) return;
  float s = 0.f;
  for (int ks = 0; ks < ksplit; ++ks) s += part[((size_t)(ks * R3_ + row)) * EA_ + e];
  int g = row / BT_;
  float a = ws[OFF_AB + g * 2], bb = ws[OFF_AB + g * 2 + 1];
  ws[OFF_RT + (size_t)e * R3_ + row] = fmaf(a, s, fmaf(bb, ws[OFF_CS + e], ltb[e]));
}

// qkv epilogue -> P[row144][9000]
__global__ void k_epiQkv(const float* __restrict__ part, const float* __restrict__ qkvb,
                         float* __restrict__ P, int ksplit) {
  int c = blockIdx.x * 256 + threadIdx.x;
  int row = blockIdx.y;
  if (c >= 3 * EA_) return;
  float s = 0.f;
  for (int ks = 0; ks < ksplit; ++ks) s += part[((size_t)(ks * R3_ + row)) * (3 * EA_) + c];
  P[(size_t)row * (3 * EA_) + c] = s + qkvb[c];
}

// attention core (tiny): one block per (mha, s, b, h)
__global__ void k_attn(const float* __restrict__ P, float* __restrict__ AoT) {
  int mha = blockIdx.y;
  int s_ = blockIdx.x / (B_ * H_);
  int rem = blockIdx.x % (B_ * H_);
  int b = rem / H_, h = rem % H_;
  const int pq[3] = {0, 1, 2}, pk[3] = {1, 2, 0}, pv[3] = {2, 0, 1};
  const float* qrow = P + ((size_t)(pq[mha] * BT_ + s_ * B_ + b)) * (3 * EA_) + h * HD_;
  __shared__ float sc[T_];
  __shared__ float red[4];
  for (int t = 0; t < T_; ++t) {
    const float* krow = P + ((size_t)(pk[mha] * BT_ + t * B_ + b)) * (3 * EA_) + EA_ + h * HD_;
    float p = 0.f;
    for (int d = threadIdx.x; d < HD_; d += 256) p = fmaf(qrow[d], krow[d], p);
    p = waveReduceSum(p);
    if ((threadIdx.x & 63) == 0) red[threadIdx.x >> 6] = p;
    __syncthreads();
    if (threadIdx.x == 0) sc[t] = (red[0] + red[1] + red[2] + red[3]) * 0.031622776601683794f;
    __syncthreads();
  }
  float a[T_];
  float m = sc[0];
#pragma unroll
  for (int t = 1; t < T_; ++t) m = fmaxf(m, sc[t]);
  float sum = 0.f;
#pragma unroll
  for (int t = 0; t < T_; ++t) { a[t] = expf(sc[t] - m); sum += a[t]; }
  float inv = 1.f / sum;
#pragma unroll
  for (int t = 0; t < T_; ++t) a[t] *= inv;
  int orow = mha * BT_ + s_ * B_ + b;
  for (int d = threadIdx.x; d < HD_; d += 256) {
    float o = 0.f;
#pragma unroll
    for (int t = 0; t < T_; ++t)
      o = fmaf(a[t], P[((size_t)(pv[mha] * BT_ + t * B_ + b)) * (3 * EA_) + 2 * EA_ + h * HD_ + d], o);
    AoT[(size_t)(h * HD_ + d) * R3_ + orow] = o;
  }
}

// attn-out epilogue -> OT[c][row144]
__global__ void k_epiAO(const float* __restrict__ part, const float* __restrict__ aob,
                        float* __restrict__ OT, int ksplit) {
  int c = blockIdx.x * 256 + threadIdx.x;
  int row = blockIdx.y;
  if (c >= EA_) return;
  float s = 0.f;
  for (int ks = 0; ks < ksplit; ++ks) s += part[((size_t)(ks * R3_ + row)) * EA_ + c];
  OT[(size_t)c * R3_ + row] = s + aob[c];
}

// ll epilogue: sum three mha branches -> out2_pre[b][t*N+n] (with BETA and 3*bias)
__global__ void k_epiLL(const float* __restrict__ part, const float* __restrict__ llb,
                        float* __restrict__ o2p, int ksplit) {
  int n = blockIdx.x * 256 + threadIdx.x;
  int row = blockIdx.y;  // t*B+b
  if (n >= N_) return;
  float s = 0.f;
  for (int g = 0; g < 3; ++g)
    for (int ks = 0; ks < ksplit; ++ks)
      s += part[((size_t)(ks * R3_ + g * BT_ + row)) * N_ + n];
  int t = row / B_, b = row % B_;
  o2p[(size_t)b * (T_ * N_) + t * N_ + n] = BETA_ * (s + 3.f * llb[n]);
}

// trunk projection outp[b,t,n]
__global__ void k_proj(const float* __restrict__ out4, const float* __restrict__ pw,
                       const float* __restrict__ pb, float* __restrict__ outp) {
  int i = blockIdx.x * 256 + threadIdx.x;
  if (i >= BTN_) return;
  int b = i / (T_ * N_);
  int t = (i / N_) % T_;
  int n = i % N_;
  float acc = pb[t];
  for (int t2 = 0; t2 < T_; ++t2) {
    const float* o = out4 + ((size_t)(b * T_ + t2) * N_ + n) * D_;
#pragma unroll
    for (int d = 0; d < D_; ++d) acc = fmaf(o[d], pw[(t2 * D_ + d) * T_ + t], acc);
  }
  outp[i] = acc;
}

// p2 (replicates the reshape(-1,T) quirk exactly)
__global__ void k_p2(const float* __restrict__ o2p, const float* __restrict__ p2w,
                     const float* __restrict__ p2b, float* __restrict__ o2f) {
  int i = blockIdx.x * 256 + threadIdx.x;
  if (i >= BTN_) return;
  int b = i / (T_ * N_);
  int t = (i / N_) % T_;
  int n = i % N_;
  float acc = p2b[t];
  const float* src = o2p + (size_t)b * (T_ * N_) + (size_t)n * T_;
#pragma unroll
  for (int c = 0; c < T_; ++c) acc = fmaf(src[c], p2w[c * T_ + t], acc);
  o2f[i] = acc;
}

__global__ void k_out3(const float* __restrict__ outp, const float* __restrict__ o2f,
                       float* __restrict__ dout) {
  int i = blockIdx.x * 256 + threadIdx.x;
  if (i < BTN_) dout[i] = outp[i] + o2f[i];
}

// row-normalize f1 (x10 for /0.1) and f2
__global__ void k_fnorm(const float* __restrict__ outp, const float* __restrict__ o2f,
                        float* __restrict__ g1, float* __restrict__ g2) {
  int r = blockIdx.x * 256 + threadIdx.x;
  if (r >= B_ * N_) return;
  int b = r / N_, n = r % N_;
  float v1[T_], v2[T_];
  float s1 = 0.f, s2 = 0.f;
#pragma unroll
  for (int t = 0; t < T_; ++t) {
    v1[t] = outp[(size_t)b * T_ * N_ + t * N_ + n];
    v2[t] = o2f[(size_t)b * T_ * N_ + t * N_ + n];
    s1 = fmaf(v1[t], v1[t], s1);
    s2 = fmaf(v2[t], v2[t], s2);
  }
  float n1 = fmaxf(sqrtf(s1), 1e-12f), n2 = fmaxf(sqrtf(s2), 1e-12f);
  float i1 = 10.f / n1, i2 = 1.f / n2;
#pragma unroll
  for (int t = 0; t < T_; ++t) {
    g1[(size_t)r * T_ + t] = v1[t] * i1;
    g2[(size_t)r * T_ + t] = v2[t] * i2;
  }
}

// per-row logsumexp + diagonal of sim (16 rows per block)
__global__ void k_lse(const float* __restrict__ g1, const float* __restrict__ g2,
                      float* __restrict__ li) {
  constexpr int TI = 16;
  int i0 = blockIdx.x * TI;
  __shared__ float q[TI][T_];
  __shared__ float sdiag[TI];
  if (threadIdx.x < TI * T_)
    q[threadIdx.x / T_][threadIdx.x % T_] = g1[(size_t)i0 * T_ + threadIdx.x];
  __syncthreads();
  float sm[TI];
#pragma unroll
  for (int ii = 0; ii < TI; ++ii) sm[ii] = 0.f;
  for (int j = threadIdx.x; j < B_ * N_; j += 256) {
    const float4* p = (const float4*)(g2 + (size_t)j * T_);
    float4 A = p[0], Bv = p[1], C = p[2];
    float v[T_] = {A.x, A.y, A.z, A.w, Bv.x, Bv.y, Bv.z, Bv.w, C.x, C.y, C.z, C.w};
#pragma unroll
    for (int ii = 0; ii < TI; ++ii) {
      float s = 0.f;
#pragma unroll
      for (int t = 0; t < T_; ++t) s = fmaf(q[ii][t], v[t], s);
      sm[ii] += __expf(s);
      if (j == i0 + ii) sdiag[ii] = s;
    }
  }
  __syncthreads();
  __shared__ float red[256];
  for (int ii = 0; ii < TI; ++ii) {
    red[threadIdx.x] = sm[ii];
    __syncthreads();
    for (int st = 128; st; st >>= 1) {
      if (threadIdx.x < st) red[threadIdx.x] += red[threadIdx.x + st];
      __syncthreads();
    }
    if (threadIdx.x == 0) li[i0 + ii] = sdiag[ii] - logf(red[0]);
    __syncthreads();
  }
}

__global__ void k_final(const float* __restrict__ li, const float* __restrict__ ws,
                        float* __restrict__ dout) {
  float s = 0.f;
  for (int i = threadIdx.x; i < B_ * N_; i += 256) s += li[i];
  __shared__ float red[4];
  s = waveReduceSum(s);
  if ((threadIdx.x & 63) == 0) red[threadIdx.x >> 6] = s;
  __syncthreads();
  if (threadIdx.x == 0) {
    float closs = -(red[0] + red[1] + red[2] + red[3]) * (1.f / (B_ * N_));
    dout[BTN_] = ws[OFF_BAL];
    dout[BTN_ + 1] = CW_ * closs;
  }
}

// ---------------------------------------------------------------------------
extern "C" void kernel_launch(void* const* d_in, const int* in_sizes, int n_in,
                              void* d_out, int out_size, void* d_ws, size_t ws_size,
                              hipStream_t stream) {
  const float* x    = (const float*)d_in[0];
  const float* velo = (const float*)d_in[1];
  const float* adj  = (const float*)d_in[2];
  const float* lapd = (const float*)d_in[3];
  const float* laph = (const float*)d_in[4];
  const float* sw   = (const float*)d_in[5];
  const float* sb   = (const float*)d_in[6];
  const float* gw   = (const float*)d_in[7];
  const float* ew1  = (const float*)d_in[8];
  const float* eb1  = (const float*)d_in[9];
  const float* ew2  = (const float*)d_in[10];
  const float* eb2  = (const float*)d_in[11];
  const float* pw   = (const float*)d_in[12];
  const float* pb   = (const float*)d_in[13];
  const float* ltw  = (const float*)d_in[14];
  const float* ltb  = (const float*)d_in[15];
  const float* qkvw = (const float*)d_in[16];
  const float* qkvb = (const float*)d_in[17];
  const float* aow  = (const float*)d_in[18];
  const float* aob  = (const float*)d_in[19];
  const float* llw  = (const float*)d_in[20];
  const float* llb  = (const float*)d_in[21];
  const float* p2w  = (const float*)d_in[22];
  const float* p2b  = (const float*)d_in[23];
  float* ws = (float*)d_ws;
  float* dout = (float*)d_out;
  const float* v0 = velo;  // velo[0,0,:]
  float* part = ws + OFF_PART;
  dim3 b256(256);

  k_init<<<dim3(1), dim3(64), 0, stream>>>(ws);
  k_start<<<dim3((BTN_ * D_ + 255) / 256), b256, 0, stream>>>(x, sw, sb, ws + OFF_OUT4);

  for (int l = 0; l < L_; ++l) {
    k_feat<<<dim3(B_ * D_), b256, 0, stream>>>(ws + OFF_OUT4, ws + OFF_FEAT);
    k_gate<<<dim3(1), dim3(64), 0, stream>>>(ws + OFF_FEAT, gw, ws, l);
    k_expert<<<dim3((T_ * N_ + 255) / 256, B_), b256, 0, stream>>>(ws + OFF_OUT4, ew1, eb1, ew2, eb2, ws, l);
  }

  k_wavelet<<<dim3((BTN_ + 255) / 256), b256, 0, stream>>>(x, velo, ws + OFF_LOWT, ws + OFF_HVT);
  k_rowsum<<<dim3(2 * BT_), b256, 0, stream>>>(ws + OFF_LOWT, ws + OFF_HVT, ws);
  k_S<<<dim3(N_), b256, 0, stream>>>(adj, v0, ws + OFF_S);
  k_stats<<<dim3(512), b256, 0, stream>>>(lapd, ws + OFF_STP);
  k_stats2<<<dim3(1), b256, 0, stream>>>(ws + OFF_STP, ws + OFF_STAT);
  k_stats<<<dim3(512), b256, 0, stream>>>(laph, ws + OFF_STP + 1024);
  k_stats2<<<dim3(1), b256, 0, stream>>>(ws + OFF_STP + 1024, ws + OFF_STAT + 2);
  k_nsstats<<<dim3(512), b256, 0, stream>>>(adj, v0, ws + OFF_S, ws + OFF_STP + 2048);
  k_stats2<<<dim3(1), b256, 0, stream>>>(ws + OFF_STP + 2048, ws + OFF_STAT + 4);

  // r1 / r2 / r3 with fused normalization
  k_gemm48<<<dim3(8, 16, 1), b256, 0, stream>>>(ws + OFF_LOWT, BT_, BT_, lapd, part, N_, N_, 125);
  k_epiR<<<dim3(8, 48), b256, 0, stream>>>(part, ws, 16, 0, 0, OFF_RSL);
  k_gemmNS<<<dim3(8, 16), b256, 0, stream>>>(ws + OFF_HVT, adj, v0, ws + OFF_S, part, 125);
  k_epiR<<<dim3(8, 48), b256, 0, stream>>>(part, ws, 16, 1, 4, OFF_RSH);
  k_gemm48<<<dim3(8, 16, 1), b256, 0, stream>>>(ws + OFF_LOWT, BT_, BT_, laph, part, N_, N_, 125);
  k_epiR<<<dim3(8, 48), b256, 0, stream>>>(part, ws, 16, 2, 2, OFF_RSL);

  k_minmax<<<dim3(64, 3), b256, 0, stream>>>(ws + OFF_ALIN, ws + OFF_MMP);
  k_minmax2<<<dim3(3), dim3(64), 0, stream>>>(ws);
  k_colsum<<<dim3(12, 16), b256, 0, stream>>>(ltw, ws + OFF_CSP);
  k_colsum2<<<dim3(12), b256, 0, stream>>>(ws);

  // lin: [144,2000] @ lt_w  (3 row-groups of 48)
  k_gemm48<<<dim3(12, 16, 3), b256, 0, stream>>>(ws + OFF_ALIN, R3_, R3_, ltw, part, N_, EA_, 125);
  k_epiLin<<<dim3(12, 144), b256, 0, stream>>>(part, ltb, ws, 16);

  // qkv: [144,3000] @ qkv_w[3000,9000]
  int qks = (ws_size >= (OFF_PART + (size_t)8 * R3_ * 3 * EA_) * 4) ? 8 : 4;
  k_gemm48<<<dim3(36, qks, 3), b256, 0, stream>>>(ws + OFF_RT, R3_, R3_, qkvw, part, EA_, 3 * EA_, (EA_ + qks - 1) / qks);
  k_epiQkv<<<dim3(36, 144), b256, 0, stream>>>(part, qkvb, ws + OFF_P, qks);

  // attention (3 mha in grid.y)
  k_attn<<<dim3(T_ * B_ * H_, 3), b256, 0, stream>>>(ws + OFF_P, ws + OFF_AOT);

  // attn out projection
  k_gemm48<<<dim3(12, 16, 3), b256, 0, stream>>>(ws + OFF_AOT, R3_, R3_, aow, part, EA_, EA_, 188);
  k_epiAO<<<dim3(12, 144), b256, 0, stream>>>(part, aob, ws + OFF_OT, 16);

  // ll (back) projection + branch sum
  k_gemm48<<<dim3(8, 16, 3), b256, 0, stream>>>(ws + OFF_OT, R3_, R3_, llw, part, EA_, N_, 188);
  k_epiLL<<<dim3(8, 48), b256, 0, stream>>>(part, llb, ws + OFF_O2P, 16);

  k_proj<<<dim3((BTN_ + 255) / 256), b256, 0, stream>>>(ws + OFF_OUT4, pw, pb, ws + OFF_OUTP);
  k_p2<<<dim3((BTN_ + 255) / 256), b256, 0, stream>>>(ws + OFF_O2P, p2w, p2b, ws + OFF_O2F);
  k_out3<<<dim3((BTN_ + 255) / 256), b256, 0, stream>>>(ws + OFF_OUTP, ws + OFF_O2F, dout);

  k_fnorm<<<dim3((B_ * N_ + 255) / 256), b256, 0, stream>>>(ws + OFF_OUTP, ws + OFF_O2F, ws + OFF_G1, ws + OFF_G2);
  k_lse<<<dim3(B_ * N_ / 16), b256, 0, stream>>>(ws + OFF_G1, ws + OFF_G2, ws + OFF_LI);
  k_final<<<dim3(1), b256, 0, stream>>>(ws + OFF_LI, ws, dout);
}

// Round 3
// 1184.860 us; speedup vs baseline: 3.6421x; 1.2019x over previous
//
#include <hip/hip_runtime.h>
#include <math.h>

// ---------------------------------------------------------------------------
// Model constants
// ---------------------------------------------------------------------------
namespace {
constexpr int B_ = 4, T_ = 12, N_ = 2000, D_ = 16, FF_ = 64, E_ = 4, L_ = 2;
constexpr int EA_ = 3000, H_ = 3, HD_ = EA_ / H_;   // 1000
constexpr int BT_ = B_ * T_;                         // 48 rows per r-group
constexpr int R3_ = 3 * BT_;                         // 144 stacked rows
constexpr long long NN_ = (long long)N_ * N_;        // 4,000,000
constexpr int BTN_ = B_ * T_ * N_;                   // 96,000
constexpr float BETA_ = 0.01f, CW_ = 0.001f;

// ---------------------------------------------------------------------------
// Workspace layout (float offsets)
// ---------------------------------------------------------------------------
constexpr size_t OFF_OUT4 = 0;                                   // [B,T,N,D]
constexpr size_t OFF_LOWT = OFF_OUT4 + (size_t)BTN_ * D_;        // lowT^T [N][48]
constexpr size_t OFF_HVT  = OFF_LOWT + BTN_;                     // highV^T [N][48]
constexpr size_t OFF_ALIN = OFF_HVT + BTN_;                      // r^T [N][144]
constexpr size_t OFF_RT   = OFF_ALIN + (size_t)N_ * R3_;         // R^T [EA][144]
constexpr size_t OFF_P    = OFF_RT + (size_t)EA_ * R3_;          // P [144][9000]
constexpr size_t OFF_AOT  = OFF_P + (size_t)R3_ * 3 * EA_;       // Ao^T [EA][144]
constexpr size_t OFF_OT   = OFF_AOT + (size_t)EA_ * R3_;         // O^T  [EA][144]
constexpr size_t OFF_O2P  = OFF_OT + (size_t)EA_ * R3_;          // out2 pre-p2 [B][T*N]
constexpr size_t OFF_OUTP = OFF_O2P + BTN_;                      // outp [B,T,N]
constexpr size_t OFF_O2F  = OFF_OUTP + BTN_;                     // out2 final [B,T,N]
constexpr size_t OFF_G1   = OFF_O2F + BTN_;                      // f1 normalized*10 [8000][12]
constexpr size_t OFF_G2   = OFF_G1 + 96000;                      // f2 normalized [8000][12]
constexpr size_t OFF_LI   = OFF_G2 + 96000;                      // li [8000]
constexpr size_t OFF_S    = OFF_LI + 8000;                       // G row sums [2000]
constexpr size_t OFF_RSL  = OFF_S + 2000;                        // rowsum lowT [48]
constexpr size_t OFF_RSH  = OFF_RSL + 48;                        // rowsum hv [48]
constexpr size_t OFF_STP  = OFF_RSH + 48;                        // stat partials 3*512*2
constexpr size_t OFF_STAT = OFF_STP + 3072;                      // {mu,isd} x3
constexpr size_t OFF_MMP  = OFF_STAT + 8;                        // minmax partials [3][64][2]
constexpr size_t OFF_AB   = OFF_MMP + 384;                       // {alpha,beta} x3
constexpr size_t OFF_CSP  = OFF_AB + 8;                          // colsum partials [16][3000]
constexpr size_t OFF_CS   = OFF_CSP + 48000;                     // lt_w colsums [3000]
constexpr size_t OFF_FEAT = OFF_CS + 3000;                       // feat [B][D]
constexpr size_t OFF_GATE = OFF_FEAT + 64;                       // gates [B][E]
constexpr size_t OFF_BAL  = OFF_GATE + 16;                       // balance scalar
constexpr size_t OFF_PART = ((OFF_BAL + 1 + 255) & ~(size_t)255); // GEMM split-K partials
} // namespace

// ---------------------------------------------------------------------------
// Small helpers
// ---------------------------------------------------------------------------
__device__ __forceinline__ float waveReduceSum(float v) {
  for (int off = 32; off; off >>= 1) v += __shfl_down(v, off);
  return v;
}

// ---------------------------------------------------------------------------
__global__ void k_init(float* ws) {
  if (threadIdx.x == 0) ws[OFF_BAL] = 0.f;
}

// out4[b,t,n,d] = x[b,t,n]*sw[d] + sb[d]
__global__ void k_start(const float* __restrict__ x, const float* __restrict__ sw,
                        const float* __restrict__ sb, float* __restrict__ out4) {
  int i = blockIdx.x * 256 + threadIdx.x;
  if (i >= BTN_ * D_) return;
  int d = i & 15;
  out4[i] = fmaf(x[i >> 4], sw[d], sb[d]);
}

// feat[b,d] = mean over (t,n) of out4
__global__ void k_feat(const float* __restrict__ out4, float* __restrict__ feat) {
  int b = blockIdx.x >> 4, d = blockIdx.x & 15;
  float s = 0.f;
  for (int tn = threadIdx.x; tn < T_ * N_; tn += 256)
    s += out4[((size_t)b * T_ * N_ + tn) * D_ + d];
  __shared__ float red[4];
  s = waveReduceSum(s);
  if ((threadIdx.x & 63) == 0) red[threadIdx.x >> 6] = s;
  __syncthreads();
  if (threadIdx.x == 0)
    feat[blockIdx.x] = (red[0] + red[1] + red[2] + red[3]) * (1.f / (T_ * N_));
}

// logits -> top2 -> gates + balance accumulation (single block)
__global__ void k_gate(const float* __restrict__ feat, const float* __restrict__ gw,
                       float* __restrict__ ws, int l) {
  __shared__ float lg[B_ * E_];
  int tid = threadIdx.x;
  if (tid < B_ * E_) {
    int b = tid >> 2, e = tid & 3;
    float s = 0.f;
    for (int d = 0; d < D_; ++d) s = fmaf(feat[b * D_ + d], gw[(l * D_ + d) * E_ + e], s);
    lg[tid] = s;
  }
  __syncthreads();
  if (tid == 0) {
    float* gates = ws + OFF_GATE;
    float imp[E_] = {0, 0, 0, 0}, load[E_] = {0, 0, 0, 0};
    for (int i = 0; i < B_ * E_; ++i) gates[i] = 0.f;
    for (int b = 0; b < B_; ++b) {
      const float* lb = lg + b * E_;
      int i1 = 0; float v1 = lb[0];
      for (int e = 1; e < E_; ++e) if (lb[e] > v1) { v1 = lb[e]; i1 = e; }
      int i2 = -1; float v2 = -1e30f;
      for (int e = 0; e < E_; ++e) { if (e == i1) continue; if (lb[e] > v2) { v2 = lb[e]; i2 = e; } }
      float e2 = expf(v2 - v1);
      float den = 1.f + e2;
      float g1 = 1.f / den, g2 = e2 / den;
      gates[b * E_ + i1] = g1; gates[b * E_ + i2] = g2;
      imp[i1] += g1; imp[i2] += g2; load[i1] += 1.f; load[i2] += 1.f;
    }
    float bal = 0.f;
    float m = 0.f; for (int e = 0; e < E_; ++e) m += imp[e]; m *= 0.25f;
    float v = 0.f; for (int e = 0; e < E_; ++e) { float d = imp[e] - m; v += d * d; } v *= 0.25f;
    bal += v / (m * m + 1e-10f);
    m = 0.f; for (int e = 0; e < E_; ++e) m += load[e]; m *= 0.25f;
    v = 0.f; for (int e = 0; e < E_; ++e) { float d = load[e] - m; v += d * d; } v *= 0.25f;
    bal += v / (m * m + 1e-10f);
    ws[OFF_BAL] += bal;
  }
}

// MoE expert apply (in-place residual), layer l
__global__ void k_expert(float* __restrict__ out4, const float* __restrict__ w1,
                         const float* __restrict__ b1, const float* __restrict__ w2,
                         const float* __restrict__ b2, const float* __restrict__ ws, int l) {
  int b = blockIdx.y;
  int tn = blockIdx.x * 256 + threadIdx.x;
  if (tn >= T_ * N_) return;
  float* row = out4 + ((size_t)b * T_ * N_ + tn) * D_;
  float r[D_], acc[D_];
#pragma unroll
  for (int d = 0; d < D_; ++d) { r[d] = row[d]; acc[d] = r[d]; }
  const float* gates = ws + OFF_GATE;
  for (int e = 0; e < E_; ++e) {
    float g = gates[b * E_ + e];
    if (g <= 0.f) continue;
    const float* W1 = w1 + (size_t)(l * E_ + e) * D_ * FF_;
    const float* B1 = b1 + (size_t)(l * E_ + e) * FF_;
    const float* W2 = w2 + (size_t)(l * E_ + e) * FF_ * D_;
    const float* B2 = b2 + (size_t)(l * E_ + e) * D_;
#pragma unroll 4
    for (int f = 0; f < FF_; ++f) {
      float p = B1[f];
#pragma unroll
      for (int d = 0; d < D_; ++d) p = fmaf(r[d], W1[d * FF_ + f], p);
      float c = 0.7978845608028654f * (p + 0.044715f * p * p * p);
      float hv = 0.5f * p * (1.f + tanhf(c));
      float gh = g * hv;
#pragma unroll
      for (int d = 0; d < D_; ++d) acc[d] = fmaf(gh, W2[f * D_ + d], acc[d]);
    }
#pragma unroll
    for (int d = 0; d < D_; ++d) acc[d] = fmaf(g, B2[d], acc[d]);
  }
#pragma unroll
  for (int d = 0; d < D_; ++d) row[d] = acc[d];
}

// wavelet split; writes transposed [n][row], row = t*B+b
__global__ void k_wavelet(const float* __restrict__ x, const float* __restrict__ velo,
                          float* __restrict__ lowT, float* __restrict__ hvT) {
  int i = blockIdx.x * 256 + threadIdx.x;
  if (i >= BTN_) return;
  int b = i / (T_ * N_);
  int t = (i / N_) % T_;
  int n = i % N_;
  int ip = b * T_ * N_ + ((t + T_ - 1) % T_) * N_ + n;
  int row = t * B_ + b;
  lowT[(size_t)n * BT_ + row] = 0.5f * (x[i] + x[ip]);
  hvT[(size_t)n * BT_ + row] = 0.5f * (velo[i] - velo[ip]);
}

// row sums of lowT / hvT (96 blocks)
__global__ void k_rowsum(const float* __restrict__ lowT, const float* __restrict__ hvT,
                         float* __restrict__ ws) {
  int which = blockIdx.x / BT_;
  int row = blockIdx.x % BT_;
  const float* M = which ? hvT : lowT;
  float s = 0.f;
  for (int n = threadIdx.x; n < N_; n += 256) s += M[(size_t)n * BT_ + row];
  __shared__ float red[4];
  s = waveReduceSum(s);
  if ((threadIdx.x & 63) == 0) red[threadIdx.x >> 6] = s;
  __syncthreads();
  if (threadIdx.x == 0) ws[(which ? OFF_RSH : OFF_RSL) + row] = red[0] + red[1] + red[2] + red[3];
}

// S[m] = sum_n v0[m]/adj[m,n]
__global__ void k_S(const float* __restrict__ adj, const float* __restrict__ v0,
                    float* __restrict__ S) {
  int m = blockIdx.x;
  float vm = v0[m];
  const float* a = adj + (size_t)m * N_;
  float s = 0.f;
  for (int n = threadIdx.x; n < N_; n += 256) s += vm / a[n];
  __shared__ float red[4];
  s = waveReduceSum(s);
  if ((threadIdx.x & 63) == 0) red[threadIdx.x >> 6] = s;
  __syncthreads();
  if (threadIdx.x == 0) S[m] = red[0] + red[1] + red[2] + red[3];
}

// sum / sumsq of a dense NxN matrix  (512 blocks)
__global__ void k_stats(const float* __restrict__ M, float* __restrict__ part) {
  float s = 0.f, ss = 0.f;
  for (long long i = blockIdx.x * 256 + threadIdx.x; i < NN_; i += 512 * 256) {
    float v = M[i];
    s += v; ss = fmaf(v, v, ss);
  }
  __shared__ float r1[4], r2[4];
  for (int off = 32; off; off >>= 1) { s += __shfl_down(s, off); ss += __shfl_down(ss, off); }
  if ((threadIdx.x & 63) == 0) { r1[threadIdx.x >> 6] = s; r2[threadIdx.x >> 6] = ss; }
  __syncthreads();
  if (threadIdx.x == 0) {
    part[blockIdx.x * 2] = r1[0] + r1[1] + r1[2] + r1[3];
    part[blockIdx.x * 2 + 1] = r2[0] + r2[1] + r2[2] + r2[3];
  }
}

// same but for the on-the-fly NS laplacian
__global__ void k_nsstats(const float* __restrict__ adj, const float* __restrict__ v0,
                          const float* __restrict__ S, float* __restrict__ part) {
  float s = 0.f, ss = 0.f;
  for (long long i = blockIdx.x * 256 + threadIdx.x; i < NN_; i += 512 * 256) {
    int m = (int)(i / N_), n = (int)(i % N_);
    float e = -(v0[m] / adj[i]);
    if (m == n) e += S[m];
    s += e; ss = fmaf(e, e, ss);
  }
  __shared__ float r1[4], r2[4];
  for (int off = 32; off; off >>= 1) { s += __shfl_down(s, off); ss += __shfl_down(ss, off); }
  if ((threadIdx.x & 63) == 0) { r1[threadIdx.x >> 6] = s; r2[threadIdx.x >> 6] = ss; }
  __syncthreads();
  if (threadIdx.x == 0) {
    part[blockIdx.x * 2] = r1[0] + r1[1] + r1[2] + r1[3];
    part[blockIdx.x * 2 + 1] = r2[0] + r2[1] + r2[2] + r2[3];
  }
}

// combine 512 {sum,sumsq} partials -> {mu, 1/std}
__global__ void k_stats2(const float* __restrict__ part, float* __restrict__ stat) {
  float s = 0.f, ss = 0.f;
  for (int i = threadIdx.x; i < 512; i += 256) { s += part[i * 2]; ss += part[i * 2 + 1]; }
  __shared__ float r1[4], r2[4];
  for (int off = 32; off; off >>= 1) { s += __shfl_down(s, off); ss += __shfl_down(ss, off); }
  if ((threadIdx.x & 63) == 0) { r1[threadIdx.x >> 6] = s; r2[threadIdx.x >> 6] = ss; }
  __syncthreads();
  if (threadIdx.x == 0) {
    float su = r1[0] + r1[1] + r1[2] + r1[3];
    float sq = r2[0] + r2[1] + r2[2] + r2[3];
    float mu = su * (1.f / (float)NN_);
    float var = sq * (1.f / (float)NN_) - mu * mu;
    stat[0] = mu;
    stat[1] = 1.f / sqrtf(var);
  }
}

// ---------------------------------------------------------------------------
// Skinny streaming GEMM, 48 accumulator rows per block, float4 A-loads.
// Row-groups of a taller A are handled by blockIdx.z: rows [g*48, g*48+48).
// part[(ks*rowTot + g*48 + r)*NC + col] = partial over K-chunk ks.
// ---------------------------------------------------------------------------
__global__ __launch_bounds__(256) void k_gemm48(
    const float* __restrict__ AT, int lda, int rowTot,
    const float* __restrict__ Bm, float* __restrict__ part,
    int Kdim, int NC, int kchunk) {
  int col = blockIdx.x * 256 + threadIdx.x;
  int g = blockIdx.z;
  int m0 = blockIdx.y * kchunk;
  int m1 = min(Kdim, m0 + kchunk);
  float acc[BT_];
#pragma unroll
  for (int r = 0; r < BT_; ++r) acc[r] = 0.f;
  if (col < NC) {
    const float* bp = Bm + (size_t)m0 * NC + col;
    const float* ap = AT + (size_t)m0 * lda + g * BT_;
    for (int m = m0; m < m1; ++m, bp += NC, ap += lda) {
      float bv = *bp;
      const float4* a4 = (const float4*)ap;
#pragma unroll
      for (int r4 = 0; r4 < BT_ / 4; ++r4) {
        float4 av = a4[r4];
        acc[r4 * 4 + 0] = fmaf(av.x, bv, acc[r4 * 4 + 0]);
        acc[r4 * 4 + 1] = fmaf(av.y, bv, acc[r4 * 4 + 1]);
        acc[r4 * 4 + 2] = fmaf(av.z, bv, acc[r4 * 4 + 2]);
        acc[r4 * 4 + 3] = fmaf(av.w, bv, acc[r4 * 4 + 3]);
      }
    }
    float* pp = part + ((size_t)blockIdx.y * rowTot + g * BT_) * NC + col;
#pragma unroll
    for (int r = 0; r < BT_; ++r) pp[(size_t)r * NC] = acc[r];
  }
}

// NS-laplacian variant: B generated on the fly from adj/v0/S
__global__ __launch_bounds__(256) void k_gemmNS(
    const float* __restrict__ hvT, const float* __restrict__ adj,
    const float* __restrict__ v0, const float* __restrict__ S,
    float* __restrict__ part, int kchunk) {
  int col = blockIdx.x * 256 + threadIdx.x;
  int m0 = blockIdx.y * kchunk;
  int m1 = min(N_, m0 + kchunk);
  float acc[BT_];
#pragma unroll
  for (int r = 0; r < BT_; ++r) acc[r] = 0.f;
  if (col < N_) {
    const float* ap = hvT + (size_t)m0 * BT_;
    for (int m = m0; m < m1; ++m, ap += BT_) {
      float bv = -(v0[m] / adj[(size_t)m * N_ + col]);
      if (m == col) bv += S[m];
      const float4* a4 = (const float4*)ap;
#pragma unroll
      for (int r4 = 0; r4 < BT_ / 4; ++r4) {
        float4 av = a4[r4];
        acc[r4 * 4 + 0] = fmaf(av.x, bv, acc[r4 * 4 + 0]);
        acc[r4 * 4 + 1] = fmaf(av.y, bv, acc[r4 * 4 + 1]);
        acc[r4 * 4 + 2] = fmaf(av.z, bv, acc[r4 * 4 + 2]);
        acc[r4 * 4 + 3] = fmaf(av.w, bv, acc[r4 * 4 + 3]);
      }
    }
    float* pp = part + (size_t)blockIdx.y * BT_ * N_ + col;
#pragma unroll
    for (int r = 0; r < BT_; ++r) pp[(size_t)r * N_] = acc[r];
  }
}

// epilogue: r matmul + fused std-normalization -> ALIN[n][g*48+row]
__global__ void k_epiR(const float* __restrict__ part, float* __restrict__ ws,
                       int ksplit, int g, int statIdx, size_t rsOff) {
  int n = blockIdx.x * 256 + threadIdx.x;
  int row = blockIdx.y;
  if (n >= N_) return;
  float s = 0.f;
  for (int ks = 0; ks < ksplit; ++ks) s += part[((size_t)(ks * BT_ + row)) * N_ + n];
  float mu = ws[OFF_STAT + statIdx], isd = ws[OFF_STAT + statIdx + 1];
  float val = (s - mu * ws[rsOff + row]) * isd;
  ws[OFF_ALIN + (size_t)n * R3_ + g * BT_ + row] = val;
}

// min/max per r-group
__global__ void k_minmax(const float* __restrict__ alin, float* __restrict__ mmp) {
  int g = blockIdx.y;
  float mn = 3.4e38f, mx = -3.4e38f;
  for (int i = blockIdx.x * 256 + threadIdx.x; i < N_ * BT_; i += 64 * 256) {
    int n = i / BT_, r = i % BT_;
    float v = alin[(size_t)n * R3_ + g * BT_ + r];
    mn = fminf(mn, v); mx = fmaxf(mx, v);
  }
  __shared__ float rn[4], rx[4];
  for (int off = 32; off; off >>= 1) {
    mn = fminf(mn, __shfl_down(mn, off));
    mx = fmaxf(mx, __shfl_down(mx, off));
  }
  if ((threadIdx.x & 63) == 0) { rn[threadIdx.x >> 6] = mn; rx[threadIdx.x >> 6] = mx; }
  __syncthreads();
  if (threadIdx.x == 0) {
    mn = fminf(fminf(rn[0], rn[1]), fminf(rn[2], rn[3]));
    mx = fmaxf(fmaxf(rx[0], rx[1]), fmaxf(rx[2], rx[3]));
    mmp[(size_t)(g * 64 + blockIdx.x) * 2] = mn;
    mmp[(size_t)(g * 64 + blockIdx.x) * 2 + 1] = mx;
  }
}

__global__ void k_minmax2(float* __restrict__ ws) {
  int g = blockIdx.x;
  int i = threadIdx.x;  // 64 threads
  float mn = ws[OFF_MMP + (size_t)(g * 64 + i) * 2];
  float mx = ws[OFF_MMP + (size_t)(g * 64 + i) * 2 + 1];
  for (int off = 32; off; off >>= 1) {
    mn = fminf(mn, __shfl_down(mn, off));
    mx = fmaxf(mx, __shfl_down(mx, off));
  }
  if (i == 0) {
    float denom = fmaxf(mx - mn, 1e-8f);
    float a = 1.f / denom;
    ws[OFF_AB + g * 2] = a;
    ws[OFF_AB + g * 2 + 1] = -mn * a;
  }
}

// lt_w column sums (two stage)
__global__ void k_colsum(const float* __restrict__ ltw, float* __restrict__ csp) {
  int e = blockIdx.x * 256 + threadIdx.x;
  int ks = blockIdx.y;
  if (e >= EA_) return;
  float s = 0.f;
  for (int n = ks * 125; n < (ks + 1) * 125; ++n) s += ltw[(size_t)n * EA_ + e];
  csp[(size_t)ks * EA_ + e] = s;
}
__global__ void k_colsum2(float* __restrict__ ws) {
  int e = blockIdx.x * 256 + threadIdx.x;
  if (e >= EA_) return;
  float s = 0.f;
  for (int ks = 0; ks < 16; ++ks) s += ws[OFF_CSP + (size_t)ks * EA_ + e];
  ws[OFF_CS + e] = s;
}

// lin epilogue: rng01 folded in -> RT[e][row144]
__global__ void k_epiLin(const float* __restrict__ part, const float* __restrict__ ltb,
                         float* __restrict__ ws, int ksplit) {
  int e = blockIdx.x * 256 + threadIdx.x;
  int row = blockIdx.y;
  if (e >= EA_) return;
  float s = 0.f;
  for (int ks = 0; ks < ksplit; ++ks) s += part[((size_t)(ks * R3_ + row)) * EA_ + e];
  int g = row / BT_;
  float a = ws[OFF_AB + g * 2], bb = ws[OFF_AB + g * 2 + 1];
  ws[OFF_RT + (size_t)e * R3_ + row] = fmaf(a, s, fmaf(bb, ws[OFF_CS + e], ltb[e]));
}

// qkv epilogue -> P[row144][9000]
__global__ void k_epiQkv(const float* __restrict__ part, const float* __restrict__ qkvb,
                         float* __restrict__ P, int ksplit) {
  int c = blockIdx.x * 256 + threadIdx.x;
  int row = blockIdx.y;
  if (c >= 3 * EA_) return;
  float s = 0.f;
  for (int ks = 0; ks < ksplit; ++ks) s += part[((size_t)(ks * R3_ + row)) * (3 * EA_) + c];
  P[(size_t)row * (3 * EA_) + c] = s + qkvb[c];
}

// attention core (tiny): one block per (mha, s, b, h)
__global__ void k_attn(const float* __restrict__ P, float* __restrict__ AoT) {
  int mha = blockIdx.y;
  int s_ = blockIdx.x / (B_ * H_);
  int rem = blockIdx.x % (B_ * H_);
  int b = rem / H_, h = rem % H_;
  const int pq[3] = {0, 1, 2}, pk[3] = {1, 2, 0}, pv[3] = {2, 0, 1};
  const float* qrow = P + ((size_t)(pq[mha] * BT_ + s_ * B_ + b)) * (3 * EA_) + h * HD_;
  __shared__ float sc[T_];
  __shared__ float red[4];
  for (int t = 0; t < T_; ++t) {
    const float* krow = P + ((size_t)(pk[mha] * BT_ + t * B_ + b)) * (3 * EA_) + EA_ + h * HD_;
    float p = 0.f;
    for (int d = threadIdx.x; d < HD_; d += 256) p = fmaf(qrow[d], krow[d], p);
    p = waveReduceSum(p);
    if ((threadIdx.x & 63) == 0) red[threadIdx.x >> 6] = p;
    __syncthreads();
    if (threadIdx.x == 0) sc[t] = (red[0] + red[1] + red[2] + red[3]) * 0.031622776601683794f;
    __syncthreads();
  }
  float a[T_];
  float m = sc[0];
#pragma unroll
  for (int t = 1; t < T_; ++t) m = fmaxf(m, sc[t]);
  float sum = 0.f;
#pragma unroll
  for (int t = 0; t < T_; ++t) { a[t] = expf(sc[t] - m); sum += a[t]; }
  float inv = 1.f / sum;
#pragma unroll
  for (int t = 0; t < T_; ++t) a[t] *= inv;
  int orow = mha * BT_ + s_ * B_ + b;
  for (int d = threadIdx.x; d < HD_; d += 256) {
    float o = 0.f;
#pragma unroll
    for (int t = 0; t < T_; ++t)
      o = fmaf(a[t], P[((size_t)(pv[mha] * BT_ + t * B_ + b)) * (3 * EA_) + 2 * EA_ + h * HD_ + d], o);
    AoT[(size_t)(h * HD_ + d) * R3_ + orow] = o;
  }
}

// attn-out epilogue -> OT[c][row144]
__global__ void k_epiAO(const float* __restrict__ part, const float* __restrict__ aob,
                        float* __restrict__ OT, int ksplit) {
  int c = blockIdx.x * 256 + threadIdx.x;
  int row = blockIdx.y;
  if (c >= EA_) return;
  float s = 0.f;
  for (int ks = 0; ks < ksplit; ++ks) s += part[((size_t)(ks * R3_ + row)) * EA_ + c];
  OT[(size_t)c * R3_ + row] = s + aob[c];
}

// ll epilogue: sum three mha branches -> out2_pre[b][t*N+n] (with BETA and 3*bias)
__global__ void k_epiLL(const float* __restrict__ part, const float* __restrict__ llb,
                        float* __restrict__ o2p, int ksplit) {
  int n = blockIdx.x * 256 + threadIdx.x;
  int row = blockIdx.y;  // t*B+b
  if (n >= N_) return;
  float s = 0.f;
  for (int g = 0; g < 3; ++g)
    for (int ks = 0; ks < ksplit; ++ks)
      s += part[((size_t)(ks * R3_ + g * BT_ + row)) * N_ + n];
  int t = row / B_, b = row % B_;
  o2p[(size_t)b * (T_ * N_) + t * N_ + n] = BETA_ * (s + 3.f * llb[n]);
}

// trunk projection outp[b,t,n]
__global__ void k_proj(const float* __restrict__ out4, const float* __restrict__ pw,
                       const float* __restrict__ pb, float* __restrict__ outp) {
  int i = blockIdx.x * 256 + threadIdx.x;
  if (i >= BTN_) return;
  int b = i / (T_ * N_);
  int t = (i / N_) % T_;
  int n = i % N_;
  float acc = pb[t];
  for (int t2 = 0; t2 < T_; ++t2) {
    const float* o = out4 + ((size_t)(b * T_ + t2) * N_ + n) * D_;
#pragma unroll
    for (int d = 0; d < D_; ++d) acc = fmaf(o[d], pw[(t2 * D_ + d) * T_ + t], acc);
  }
  outp[i] = acc;
}

// p2 (replicates the reshape(-1,T) quirk exactly)
__global__ void k_p2(const float* __restrict__ o2p, const float* __restrict__ p2w,
                     const float* __restrict__ p2b, float* __restrict__ o2f) {
  int i = blockIdx.x * 256 + threadIdx.x;
  if (i >= BTN_) return;
  int b = i / (T_ * N_);
  int t = (i / N_) % T_;
  int n = i % N_;
  float acc = p2b[t];
  const float* src = o2p + (size_t)b * (T_ * N_) + (size_t)n * T_;
#pragma unroll
  for (int c = 0; c < T_; ++c) acc = fmaf(src[c], p2w[c * T_ + t], acc);
  o2f[i] = acc;
}

__global__ void k_out3(const float* __restrict__ outp, const float* __restrict__ o2f,
                       float* __restrict__ dout) {
  int i = blockIdx.x * 256 + threadIdx.x;
  if (i < BTN_) dout[i] = outp[i] + o2f[i];
}

// row-normalize f1 (x10 for /0.1) and f2
__global__ void k_fnorm(const float* __restrict__ outp, const float* __restrict__ o2f,
                        float* __restrict__ g1, float* __restrict__ g2) {
  int r = blockIdx.x * 256 + threadIdx.x;
  if (r >= B_ * N_) return;
  int b = r / N_, n = r % N_;
  float v1[T_], v2[T_];
  float s1 = 0.f, s2 = 0.f;
#pragma unroll
  for (int t = 0; t < T_; ++t) {
    v1[t] = outp[(size_t)b * T_ * N_ + t * N_ + n];
    v2[t] = o2f[(size_t)b * T_ * N_ + t * N_ + n];
    s1 = fmaf(v1[t], v1[t], s1);
    s2 = fmaf(v2[t], v2[t], s2);
  }
  float n1 = fmaxf(sqrtf(s1), 1e-12f), n2 = fmaxf(sqrtf(s2), 1e-12f);
  float i1 = 10.f / n1, i2 = 1.f / n2;
#pragma unroll
  for (int t = 0; t < T_; ++t) {
    g1[(size_t)r * T_ + t] = v1[t] * i1;
    g2[(size_t)r * T_ + t] = v2[t] * i2;
  }
}

// per-row logsumexp + diagonal of sim.
// 16 rows per block x 16 threads per row; one accumulator per thread (no spill).
__global__ __launch_bounds__(256) void k_lse(const float* __restrict__ g1,
                                             const float* __restrict__ g2,
                                             float* __restrict__ li) {
  int r = threadIdx.x >> 4;   // 0..15 row within block
  int k = threadIdx.x & 15;   // 0..15 j-phase
  int row = blockIdx.x * 16 + r;
  const float4* qp = (const float4*)(g1 + (size_t)row * T_);
  float4 qa = qp[0], qb = qp[1], qc = qp[2];
  float sm = 0.f, sd = 0.f;
  for (int j = k; j < B_ * N_; j += 16) {
    const float4* p = (const float4*)(g2 + (size_t)j * T_);
    float4 A = p[0], Bv = p[1], C = p[2];
    float s = qa.x * A.x;
    s = fmaf(qa.y, A.y, s);  s = fmaf(qa.z, A.z, s);  s = fmaf(qa.w, A.w, s);
    s = fmaf(qb.x, Bv.x, s); s = fmaf(qb.y, Bv.y, s); s = fmaf(qb.z, Bv.z, s);
    s = fmaf(qb.w, Bv.w, s); s = fmaf(qc.x, C.x, s);  s = fmaf(qc.y, C.y, s);
    s = fmaf(qc.z, C.z, s);  s = fmaf(qc.w, C.w, s);
    sm += __expf(s);
    if (j == row) sd = s;
  }
  // reduce within the 16-lane row group (xor of lane bits 0..3 stays in-group)
#pragma unroll
  for (int off = 8; off; off >>= 1) {
    sm += __shfl_xor(sm, off);
    sd += __shfl_xor(sd, off);  // only one lane contributed; rest are 0
  }
  if (k == 0) li[row] = sd - logf(sm);
}

__global__ void k_final(const float* __restrict__ li, const float* __restrict__ ws,
                        float* __restrict__ dout) {
  float s = 0.f;
  for (int i = threadIdx.x; i < B_ * N_; i += 256) s += li[i];
  __shared__ float red[4];
  s = waveReduceSum(s);
  if ((threadIdx.x & 63) == 0) red[threadIdx.x >> 6] = s;
  __syncthreads();
  if (threadIdx.x == 0) {
    float closs = -(red[0] + red[1] + red[2] + red[3]) * (1.f / (B_ * N_));
    dout[BTN_] = ws[OFF_BAL];
    dout[BTN_ + 1] = CW_ * closs;
  }
}

// ---------------------------------------------------------------------------
extern "C" void kernel_launch(void* const* d_in, const int* in_sizes, int n_in,
                              void* d_out, int out_size, void* d_ws, size_t ws_size,
                              hipStream_t stream) {
  const float* x    = (const float*)d_in[0];
  const float* velo = (const float*)d_in[1];
  const float* adj  = (const float*)d_in[2];
  const float* lapd = (const float*)d_in[3];
  const float* laph = (const float*)d_in[4];
  const float* sw   = (const float*)d_in[5];
  const float* sb   = (const float*)d_in[6];
  const float* gw   = (const float*)d_in[7];
  const float* ew1  = (const float*)d_in[8];
  const float* eb1  = (const float*)d_in[9];
  const float* ew2  = (const float*)d_in[10];
  const float* eb2  = (const float*)d_in[11];
  const float* pw   = (const float*)d_in[12];
  const float* pb   = (const float*)d_in[13];
  const float* ltw  = (const float*)d_in[14];
  const float* ltb  = (const float*)d_in[15];
  const float* qkvw = (const float*)d_in[16];
  const float* qkvb = (const float*)d_in[17];
  const float* aow  = (const float*)d_in[18];
  const float* aob  = (const float*)d_in[19];
  const float* llw  = (const float*)d_in[20];
  const float* llb  = (const float*)d_in[21];
  const float* p2w  = (const float*)d_in[22];
  const float* p2b  = (const float*)d_in[23];
  float* ws = (float*)d_ws;
  float* dout = (float*)d_out;
  const float* v0 = velo;  // velo[0,0,:]
  float* part = ws + OFF_PART;
  dim3 b256(256);

  k_init<<<dim3(1), dim3(64), 0, stream>>>(ws);
  k_start<<<dim3((BTN_ * D_ + 255) / 256), b256, 0, stream>>>(x, sw, sb, ws + OFF_OUT4);

  for (int l = 0; l < L_; ++l) {
    k_feat<<<dim3(B_ * D_), b256, 0, stream>>>(ws + OFF_OUT4, ws + OFF_FEAT);
    k_gate<<<dim3(1), dim3(64), 0, stream>>>(ws + OFF_FEAT, gw, ws, l);
    k_expert<<<dim3((T_ * N_ + 255) / 256, B_), b256, 0, stream>>>(ws + OFF_OUT4, ew1, eb1, ew2, eb2, ws, l);
  }

  k_wavelet<<<dim3((BTN_ + 255) / 256), b256, 0, stream>>>(x, velo, ws + OFF_LOWT, ws + OFF_HVT);
  k_rowsum<<<dim3(2 * BT_), b256, 0, stream>>>(ws + OFF_LOWT, ws + OFF_HVT, ws);
  k_S<<<dim3(N_), b256, 0, stream>>>(adj, v0, ws + OFF_S);
  k_stats<<<dim3(512), b256, 0, stream>>>(lapd, ws + OFF_STP);
  k_stats2<<<dim3(1), b256, 0, stream>>>(ws + OFF_STP, ws + OFF_STAT);
  k_stats<<<dim3(512), b256, 0, stream>>>(laph, ws + OFF_STP + 1024);
  k_stats2<<<dim3(1), b256, 0, stream>>>(ws + OFF_STP + 1024, ws + OFF_STAT + 2);
  k_nsstats<<<dim3(512), b256, 0, stream>>>(adj, v0, ws + OFF_S, ws + OFF_STP + 2048);
  k_stats2<<<dim3(1), b256, 0, stream>>>(ws + OFF_STP + 2048, ws + OFF_STAT + 4);

  // r1 / r2 / r3 with fused normalization
  k_gemm48<<<dim3(8, 16, 1), b256, 0, stream>>>(ws + OFF_LOWT, BT_, BT_, lapd, part, N_, N_, 125);
  k_epiR<<<dim3(8, 48), b256, 0, stream>>>(part, ws, 16, 0, 0, OFF_RSL);
  k_gemmNS<<<dim3(8, 16), b256, 0, stream>>>(ws + OFF_HVT, adj, v0, ws + OFF_S, part, 125);
  k_epiR<<<dim3(8, 48), b256, 0, stream>>>(part, ws, 16, 1, 4, OFF_RSH);
  k_gemm48<<<dim3(8, 16, 1), b256, 0, stream>>>(ws + OFF_LOWT, BT_, BT_, laph, part, N_, N_, 125);
  k_epiR<<<dim3(8, 48), b256, 0, stream>>>(part, ws, 16, 2, 2, OFF_RSL);

  k_minmax<<<dim3(64, 3), b256, 0, stream>>>(ws + OFF_ALIN, ws + OFF_MMP);
  k_minmax2<<<dim3(3), dim3(64), 0, stream>>>(ws);
  k_colsum<<<dim3(12, 16), b256, 0, stream>>>(ltw, ws + OFF_CSP);
  k_colsum2<<<dim3(12), b256, 0, stream>>>(ws);

  // lin: [144,2000] @ lt_w  (3 row-groups of 48)
  k_gemm48<<<dim3(12, 16, 3), b256, 0, stream>>>(ws + OFF_ALIN, R3_, R3_, ltw, part, N_, EA_, 125);
  k_epiLin<<<dim3(12, 144), b256, 0, stream>>>(part, ltb, ws, 16);

  // qkv: [144,3000] @ qkv_w[3000,9000]
  int qks = (ws_size >= (OFF_PART + (size_t)8 * R3_ * 3 * EA_) * 4) ? 8 : 4;
  k_gemm48<<<dim3(36, qks, 3), b256, 0, stream>>>(ws + OFF_RT, R3_, R3_, qkvw, part, EA_, 3 * EA_, (EA_ + qks - 1) / qks);
  k_epiQkv<<<dim3(36, 144), b256, 0, stream>>>(part, qkvb, ws + OFF_P, qks);

  // attention (3 mha in grid.y)
  k_attn<<<dim3(T_ * B_ * H_, 3), b256, 0, stream>>>(ws + OFF_P, ws + OFF_AOT);

  // attn out projection
  k_gemm48<<<dim3(12, 16, 3), b256, 0, stream>>>(ws + OFF_AOT, R3_, R3_, aow, part, EA_, EA_, 188);
  k_epiAO<<<dim3(12, 144), b256, 0, stream>>>(part, aob, ws + OFF_OT, 16);

  // ll (back) projection + branch sum
  k_gemm48<<<dim3(8, 16, 3), b256, 0, stream>>>(ws + OFF_OT, R3_, R3_, llw, part, EA_, N_, 188);
  k_epiLL<<<dim3(8, 48), b256, 0, stream>>>(part, llb, ws + OFF_O2P, 16);

  k_proj<<<dim3((BTN_ + 255) / 256), b256, 0, stream>>>(ws + OFF_OUT4, pw, pb, ws + OFF_OUTP);
  k_p2<<<dim3((BTN_ + 255) / 256), b256, 0, stream>>>(ws + OFF_O2P, p2w, p2b, ws + OFF_O2F);
  k_out3<<<dim3((BTN_ + 255) / 256), b256, 0, stream>>>(ws + OFF_OUTP, ws + OFF_O2F, dout);

  k_fnorm<<<dim3((B_ * N_ + 255) / 256), b256, 0, stream>>>(ws + OFF_OUTP, ws + OFF_O2F, ws + OFF_G1, ws + OFF_G2);
  k_lse<<<dim3(B_ * N_ / 16), b256, 0, stream>>>(ws + OFF_G1, ws + OFF_G2, ws + OFF_LI);
  k_final<<<dim3(1), b256, 0, stream>>>(ws + OFF_LI, ws, dout);
}

// Round 5
// 1027.339 us; speedup vs baseline: 4.2006x; 1.1533x over previous
//
#include <hip/hip_runtime.h>
#include <math.h>

// ---------------------------------------------------------------------------
// Model constants
// ---------------------------------------------------------------------------
namespace {
constexpr int B_ = 4, T_ = 12, N_ = 2000, D_ = 16, FF_ = 64, E_ = 4, L_ = 2;
constexpr int EA_ = 3000, H_ = 3, HD_ = EA_ / H_;   // 1000
constexpr int BT_ = B_ * T_;                         // 48 rows per r-group
constexpr int R3_ = 3 * BT_;                         // 144 stacked rows
constexpr long long NN_ = (long long)N_ * N_;        // 4,000,000
constexpr int BTN_ = B_ * T_ * N_;                   // 96,000
constexpr float BETA_ = 0.01f, CW_ = 0.001f;
constexpr int RKS_ = 50;                             // r-GEMM split-K
constexpr int RKC_ = 40;                             // r-GEMM k-chunk (5 groups of 8)

// ---------------------------------------------------------------------------
// Workspace layout (float offsets)
// ---------------------------------------------------------------------------
constexpr size_t OFF_OUT4 = 0;                                   // [B,T,N,D]
constexpr size_t OFF_LOWT = OFF_OUT4 + (size_t)BTN_ * D_;        // lowT^T [N][48]
constexpr size_t OFF_HVT  = OFF_LOWT + BTN_;                     // highV^T [N][48]
constexpr size_t OFF_ALIN = OFF_HVT + BTN_;                      // r^T [N][144]
constexpr size_t OFF_RT   = OFF_ALIN + (size_t)N_ * R3_;         // R^T [EA][144]
constexpr size_t OFF_P    = OFF_RT + (size_t)EA_ * R3_;          // P [144][9000]
constexpr size_t OFF_AOT  = OFF_P + (size_t)R3_ * 3 * EA_;       // Ao^T [EA][144]
constexpr size_t OFF_OT   = OFF_AOT + (size_t)EA_ * R3_;         // O^T  [EA][144]
constexpr size_t OFF_O2P  = OFF_OT + (size_t)EA_ * R3_;          // out2 pre-p2 [B][T*N]
constexpr size_t OFF_OUTP = OFF_O2P + BTN_;                      // outp [B,T,N]
constexpr size_t OFF_O2F  = OFF_OUTP + BTN_;                     // out2 final [B,T,N]
constexpr size_t OFF_G1   = OFF_O2F + BTN_;                      // f1 normalized*10 [8000][12]
constexpr size_t OFF_G2   = OFF_G1 + 96000;                      // f2 normalized [8000][12]
constexpr size_t OFF_LI   = OFF_G2 + 96000;                      // li [8000]
constexpr size_t OFF_S    = OFF_LI + 8000;                       // G row sums [2000]
constexpr size_t OFF_RSL  = OFF_S + 2000;                        // rowsum lowT [48]
constexpr size_t OFF_RSH  = OFF_RSL + 48;                        // rowsum hv [48]
constexpr size_t OFF_STP  = OFF_RSH + 48;                        // stat partials 3*512*2
constexpr size_t OFF_STAT = OFF_STP + 3072;                      // {mu,isd} x3
constexpr size_t OFF_MMP  = OFF_STAT + 8;                        // minmax partials [3][64][2]
constexpr size_t OFF_AB   = OFF_MMP + 384;                       // {alpha,beta} x3
constexpr size_t OFF_CSP  = OFF_AB + 8;                          // colsum partials [16][3000]
constexpr size_t OFF_CS   = OFF_CSP + 48000;                     // lt_w colsums [3000]
constexpr size_t OFF_FEAT = OFF_CS + 3000;                       // feat [B][D]
constexpr size_t OFF_GATE = OFF_FEAT + 64;                       // gates [B][E]
constexpr size_t OFF_BAL  = OFF_GATE + 16;                       // balance scalar
constexpr size_t OFF_PART = ((OFF_BAL + 1 + 255) & ~(size_t)255); // GEMM split-K partials
} // namespace

// ---------------------------------------------------------------------------
// Small helpers
// ---------------------------------------------------------------------------
__device__ __forceinline__ float waveReduceSum(float v) {
  for (int off = 32; off; off >>= 1) v += __shfl_down(v, off);
  return v;
}

// 48 FMAs: acc[0..47] += a4[.] * bv  (fixed order -> bit-identical partials)
__device__ __forceinline__ void fma48(float* __restrict__ acc,
                                      const float4* __restrict__ a4, float bv) {
#pragma unroll
  for (int r4 = 0; r4 < BT_ / 4; ++r4) {
    float4 av = a4[r4];
    acc[r4 * 4 + 0] = fmaf(av.x, bv, acc[r4 * 4 + 0]);
    acc[r4 * 4 + 1] = fmaf(av.y, bv, acc[r4 * 4 + 1]);
    acc[r4 * 4 + 2] = fmaf(av.z, bv, acc[r4 * 4 + 2]);
    acc[r4 * 4 + 3] = fmaf(av.w, bv, acc[r4 * 4 + 3]);
  }
}

// ---------------------------------------------------------------------------
__global__ void k_init(float* ws) {
  if (threadIdx.x == 0) ws[OFF_BAL] = 0.f;
}

// out4[b,t,n,d] = x[b,t,n]*sw[d] + sb[d]
__global__ void k_start(const float* __restrict__ x, const float* __restrict__ sw,
                        const float* __restrict__ sb, float* __restrict__ out4) {
  int i = blockIdx.x * 256 + threadIdx.x;
  if (i >= BTN_ * D_) return;
  int d = i & 15;
  out4[i] = fmaf(x[i >> 4], sw[d], sb[d]);
}

// feat[b,d] = mean over (t,n) of out4
__global__ void k_feat(const float* __restrict__ out4, float* __restrict__ feat) {
  int b = blockIdx.x >> 4, d = blockIdx.x & 15;
  float s = 0.f;
  for (int tn = threadIdx.x; tn < T_ * N_; tn += 256)
    s += out4[((size_t)b * T_ * N_ + tn) * D_ + d];
  __shared__ float red[4];
  s = waveReduceSum(s);
  if ((threadIdx.x & 63) == 0) red[threadIdx.x >> 6] = s;
  __syncthreads();
  if (threadIdx.x == 0)
    feat[blockIdx.x] = (red[0] + red[1] + red[2] + red[3]) * (1.f / (T_ * N_));
}

// logits -> top2 -> gates + balance accumulation (single block)
__global__ void k_gate(const float* __restrict__ feat, const float* __restrict__ gw,
                       float* __restrict__ ws, int l) {
  __shared__ float lg[B_ * E_];
  int tid = threadIdx.x;
  if (tid < B_ * E_) {
    int b = tid >> 2, e = tid & 3;
    float s = 0.f;
    for (int d = 0; d < D_; ++d) s = fmaf(feat[b * D_ + d], gw[(l * D_ + d) * E_ + e], s);
    lg[tid] = s;
  }
  __syncthreads();
  if (tid == 0) {
    float* gates = ws + OFF_GATE;
    float imp[E_] = {0, 0, 0, 0}, load[E_] = {0, 0, 0, 0};
    for (int i = 0; i < B_ * E_; ++i) gates[i] = 0.f;
    for (int b = 0; b < B_; ++b) {
      const float* lb = lg + b * E_;
      int i1 = 0; float v1 = lb[0];
      for (int e = 1; e < E_; ++e) if (lb[e] > v1) { v1 = lb[e]; i1 = e; }
      int i2 = -1; float v2 = -1e30f;
      for (int e = 0; e < E_; ++e) { if (e == i1) continue; if (lb[e] > v2) { v2 = lb[e]; i2 = e; } }
      float e2 = expf(v2 - v1);
      float den = 1.f + e2;
      float g1 = 1.f / den, g2 = e2 / den;
      gates[b * E_ + i1] = g1; gates[b * E_ + i2] = g2;
      imp[i1] += g1; imp[i2] += g2; load[i1] += 1.f; load[i2] += 1.f;
    }
    float bal = 0.f;
    float m = 0.f; for (int e = 0; e < E_; ++e) m += imp[e]; m *= 0.25f;
    float v = 0.f; for (int e = 0; e < E_; ++e) { float d = imp[e] - m; v += d * d; } v *= 0.25f;
    bal += v / (m * m + 1e-10f);
    m = 0.f; for (int e = 0; e < E_; ++e) m += load[e]; m *= 0.25f;
    v = 0.f; for (int e = 0; e < E_; ++e) { float d = load[e] - m; v += d * d; } v *= 0.25f;
    bal += v / (m * m + 1e-10f);
    ws[OFF_BAL] += bal;
  }
}

// MoE expert apply (in-place residual), layer l
__global__ void k_expert(float* __restrict__ out4, const float* __restrict__ w1,
                         const float* __restrict__ b1, const float* __restrict__ w2,
                         const float* __restrict__ b2, const float* __restrict__ ws, int l) {
  int b = blockIdx.y;
  int tn = blockIdx.x * 256 + threadIdx.x;
  if (tn >= T_ * N_) return;
  float* row = out4 + ((size_t)b * T_ * N_ + tn) * D_;
  float r[D_], acc[D_];
#pragma unroll
  for (int d = 0; d < D_; ++d) { r[d] = row[d]; acc[d] = r[d]; }
  const float* gates = ws + OFF_GATE;
  for (int e = 0; e < E_; ++e) {
    float g = gates[b * E_ + e];
    if (g <= 0.f) continue;
    const float* W1 = w1 + (size_t)(l * E_ + e) * D_ * FF_;
    const float* B1 = b1 + (size_t)(l * E_ + e) * FF_;
    const float* W2 = w2 + (size_t)(l * E_ + e) * FF_ * D_;
    const float* B2 = b2 + (size_t)(l * E_ + e) * D_;
#pragma unroll 4
    for (int f = 0; f < FF_; ++f) {
      float p = B1[f];
#pragma unroll
      for (int d = 0; d < D_; ++d) p = fmaf(r[d], W1[d * FF_ + f], p);
      float c = 0.7978845608028654f * (p + 0.044715f * p * p * p);
      float hv = 0.5f * p * (1.f + tanhf(c));
      float gh = g * hv;
#pragma unroll
      for (int d = 0; d < D_; ++d) acc[d] = fmaf(gh, W2[f * D_ + d], acc[d]);
    }
#pragma unroll
    for (int d = 0; d < D_; ++d) acc[d] = fmaf(g, B2[d], acc[d]);
  }
#pragma unroll
  for (int d = 0; d < D_; ++d) row[d] = acc[d];
}

// wavelet split; writes transposed [n][row], row = t*B+b
__global__ void k_wavelet(const float* __restrict__ x, const float* __restrict__ velo,
                          float* __restrict__ lowT, float* __restrict__ hvT) {
  int i = blockIdx.x * 256 + threadIdx.x;
  if (i >= BTN_) return;
  int b = i / (T_ * N_);
  int t = (i / N_) % T_;
  int n = i % N_;
  int ip = b * T_ * N_ + ((t + T_ - 1) % T_) * N_ + n;
  int row = t * B_ + b;
  lowT[(size_t)n * BT_ + row] = 0.5f * (x[i] + x[ip]);
  hvT[(size_t)n * BT_ + row] = 0.5f * (velo[i] - velo[ip]);
}

// row sums of lowT / hvT (96 blocks)
__global__ void k_rowsum(const float* __restrict__ lowT, const float* __restrict__ hvT,
                         float* __restrict__ ws) {
  int which = blockIdx.x / BT_;
  int row = blockIdx.x % BT_;
  const float* M = which ? hvT : lowT;
  float s = 0.f;
  for (int n = threadIdx.x; n < N_; n += 256) s += M[(size_t)n * BT_ + row];
  __shared__ float red[4];
  s = waveReduceSum(s);
  if ((threadIdx.x & 63) == 0) red[threadIdx.x >> 6] = s;
  __syncthreads();
  if (threadIdx.x == 0) ws[(which ? OFF_RSH : OFF_RSL) + row] = red[0] + red[1] + red[2] + red[3];
}

// S[m] = sum_n v0[m]/adj[m,n]
__global__ void k_S(const float* __restrict__ adj, const float* __restrict__ v0,
                    float* __restrict__ S) {
  int m = blockIdx.x;
  float vm = v0[m];
  const float* a = adj + (size_t)m * N_;
  float s = 0.f;
  for (int n = threadIdx.x; n < N_; n += 256) s += vm / a[n];
  __shared__ float red[4];
  s = waveReduceSum(s);
  if ((threadIdx.x & 63) == 0) red[threadIdx.x >> 6] = s;
  __syncthreads();
  if (threadIdx.x == 0) S[m] = red[0] + red[1] + red[2] + red[3];
}

// sum / sumsq of a dense NxN matrix  (512 blocks)
__global__ void k_stats(const float* __restrict__ M, float* __restrict__ part) {
  float s = 0.f, ss = 0.f;
  for (long long i = blockIdx.x * 256 + threadIdx.x; i < NN_; i += 512 * 256) {
    float v = M[i];
    s += v; ss = fmaf(v, v, ss);
  }
  __shared__ float r1[4], r2[4];
  for (int off = 32; off; off >>= 1) { s += __shfl_down(s, off); ss += __shfl_down(ss, off); }
  if ((threadIdx.x & 63) == 0) { r1[threadIdx.x >> 6] = s; r2[threadIdx.x >> 6] = ss; }
  __syncthreads();
  if (threadIdx.x == 0) {
    part[blockIdx.x * 2] = r1[0] + r1[1] + r1[2] + r1[3];
    part[blockIdx.x * 2 + 1] = r2[0] + r2[1] + r2[2] + r2[3];
  }
}

// same but for the on-the-fly NS laplacian
__global__ void k_nsstats(const float* __restrict__ adj, const float* __restrict__ v0,
                          const float* __restrict__ S, float* __restrict__ part) {
  float s = 0.f, ss = 0.f;
  for (long long i = blockIdx.x * 256 + threadIdx.x; i < NN_; i += 512 * 256) {
    int m = (int)(i / N_), n = (int)(i % N_);
    float e = -(v0[m] / adj[i]);
    if (m == n) e += S[m];
    s += e; ss = fmaf(e, e, ss);
  }
  __shared__ float r1[4], r2[4];
  for (int off = 32; off; off >>= 1) { s += __shfl_down(s, off); ss += __shfl_down(ss, off); }
  if ((threadIdx.x & 63) == 0) { r1[threadIdx.x >> 6] = s; r2[threadIdx.x >> 6] = ss; }
  __syncthreads();
  if (threadIdx.x == 0) {
    part[blockIdx.x * 2] = r1[0] + r1[1] + r1[2] + r1[3];
    part[blockIdx.x * 2 + 1] = r2[0] + r2[1] + r2[2] + r2[3];
  }
}

// combine 512 {sum,sumsq} partials -> {mu, 1/std}
__global__ void k_stats2(const float* __restrict__ part, float* __restrict__ stat) {
  float s = 0.f, ss = 0.f;
  for (int i = threadIdx.x; i < 512; i += 256) { s += part[i * 2]; ss += part[i * 2 + 1]; }
  __shared__ float r1[4], r2[4];
  for (int off = 32; off; off >>= 1) { s += __shfl_down(s, off); ss += __shfl_down(ss, off); }
  if ((threadIdx.x & 63) == 0) { r1[threadIdx.x >> 6] = s; r2[threadIdx.x >> 6] = ss; }
  __syncthreads();
  if (threadIdx.x == 0) {
    float su = r1[0] + r1[1] + r1[2] + r1[3];
    float sq = r2[0] + r2[1] + r2[2] + r2[3];
    float mu = su * (1.f / (float)NN_);
    float var = sq * (1.f / (float)NN_) - mu * mu;
    stat[0] = mu;
    stat[1] = 1.f / sqrtf(var);
  }
}

// ---------------------------------------------------------------------------
// Skinny streaming GEMM, 48 accumulator rows per block, software-pipelined:
// groups of 8 K-steps with the next group's B values prefetched (MLP=8).
// FMA order per accumulator is unchanged -> partials bit-identical.
// ---------------------------------------------------------------------------
__global__ __launch_bounds__(256) void k_gemm48(
    const float* __restrict__ AT, int lda, int rowTot,
    const float* __restrict__ Bm, float* __restrict__ part,
    int Kdim, int NC, int kchunk) {
  int col = blockIdx.x * 256 + threadIdx.x;
  int g = blockIdx.z;
  int m0 = blockIdx.y * kchunk;
  int m1 = min(Kdim, m0 + kchunk);
  float acc[BT_];
#pragma unroll
  for (int r = 0; r < BT_; ++r) acc[r] = 0.f;
  if (col < NC) {
    const float* ap = AT + (size_t)m0 * lda + g * BT_;
    const float* bp = Bm + (size_t)m0 * NC + col;
    int len = m1 - m0;
    int ng = len >> 3;
    float bc[8];
    if (ng > 0) {
#pragma unroll
      for (int u = 0; u < 8; ++u) bc[u] = bp[(size_t)u * NC];
    }
    for (int gi = 0; gi < ng; ++gi) {
      float bn[8];
      bool more = (gi + 1 < ng);
      if (more) {
#pragma unroll
        for (int u = 0; u < 8; ++u) bn[u] = bp[(size_t)(8 + u) * NC];
      }
#pragma unroll
      for (int u = 0; u < 8; ++u)
        fma48(acc, (const float4*)(ap + (size_t)u * lda), bc[u]);
      ap += (size_t)8 * lda;
      bp += (size_t)8 * NC;
      if (more) {
#pragma unroll
        for (int u = 0; u < 8; ++u) bc[u] = bn[u];
      }
    }
    for (int m = m0 + (ng << 3); m < m1; ++m) {
      fma48(acc, (const float4*)ap, *bp);
      ap += lda;
      bp += NC;
    }
    float* pp = part + ((size_t)blockIdx.y * rowTot + g * BT_) * NC + col;
#pragma unroll
    for (int r = 0; r < BT_; ++r) pp[(size_t)r * NC] = acc[r];
  }
}

// NS-laplacian variant: B generated on the fly from adj/v0/S, same pipeline
__global__ __launch_bounds__(256) void k_gemmNS(
    const float* __restrict__ hvT, const float* __restrict__ adj,
    const float* __restrict__ v0, const float* __restrict__ S,
    float* __restrict__ part, int kchunk) {
  int col = blockIdx.x * 256 + threadIdx.x;
  int m0 = blockIdx.y * kchunk;
  int m1 = min(N_, m0 + kchunk);
  float acc[BT_];
#pragma unroll
  for (int r = 0; r < BT_; ++r) acc[r] = 0.f;
  if (col < N_) {
    const float* ap = hvT + (size_t)m0 * BT_;
    const float* jp = adj + (size_t)m0 * N_ + col;
    int len = m1 - m0;
    int ng = len >> 3;
    float jc[8];
    if (ng > 0) {
#pragma unroll
      for (int u = 0; u < 8; ++u) jc[u] = jp[(size_t)u * N_];
    }
    int m = m0;
    for (int gi = 0; gi < ng; ++gi) {
      float jn[8];
      bool more = (gi + 1 < ng);
      if (more) {
#pragma unroll
        for (int u = 0; u < 8; ++u) jn[u] = jp[(size_t)(8 + u) * N_];
      }
#pragma unroll
      for (int u = 0; u < 8; ++u) {
        float bv = -(v0[m + u] / jc[u]);
        if (m + u == col) bv += S[m + u];
        fma48(acc, (const float4*)(ap + (size_t)u * BT_), bv);
      }
      m += 8;
      ap += (size_t)8 * BT_;
      jp += (size_t)8 * N_;
      if (more) {
#pragma unroll
        for (int u = 0; u < 8; ++u) jc[u] = jn[u];
      }
    }
    for (; m < m1; ++m) {
      float bv = -(v0[m] / (*jp));
      if (m == col) bv += S[m];
      fma48(acc, (const float4*)ap, bv);
      ap += BT_;
      jp += N_;
    }
    float* pp = part + (size_t)blockIdx.y * BT_ * N_ + col;
#pragma unroll
    for (int r = 0; r < BT_; ++r) pp[(size_t)r * N_] = acc[r];
  }
}

// epilogue: r matmul + fused std-normalization -> ALIN[n][g*48+row]
__global__ void k_epiR(const float* __restrict__ part, float* __restrict__ ws,
                       int ksplit, int g, int statIdx, size_t rsOff) {
  int n = blockIdx.x * 256 + threadIdx.x;
  int row = blockIdx.y;
  if (n >= N_) return;
  float s = 0.f;
  for (int ks = 0; ks < ksplit; ++ks) s += part[((size_t)(ks * BT_ + row)) * N_ + n];
  float mu = ws[OFF_STAT + statIdx], isd = ws[OFF_STAT + statIdx + 1];
  float val = (s - mu * ws[rsOff + row]) * isd;
  ws[OFF_ALIN + (size_t)n * R3_ + g * BT_ + row] = val;
}

// min/max per r-group
__global__ void k_minmax(const float* __restrict__ alin, float* __restrict__ mmp) {
  int g = blockIdx.y;
  float mn = 3.4e38f, mx = -3.4e38f;
  for (int i = blockIdx.x * 256 + threadIdx.x; i < N_ * BT_; i += 64 * 256) {
    int n = i / BT_, r = i % BT_;
    float v = alin[(size_t)n * R3_ + g * BT_ + r];
    mn = fminf(mn, v); mx = fmaxf(mx, v);
  }
  __shared__ float rn[4], rx[4];
  for (int off = 32; off; off >>= 1) {
    mn = fminf(mn, __shfl_down(mn, off));
    mx = fmaxf(mx, __shfl_down(mx, off));
  }
  if ((threadIdx.x & 63) == 0) { rn[threadIdx.x >> 6] = mn; rx[threadIdx.x >> 6] = mx; }
  __syncthreads();
  if (threadIdx.x == 0) {
    mn = fminf(fminf(rn[0], rn[1]), fminf(rn[2], rn[3]));
    mx = fmaxf(fmaxf(rx[0], rx[1]), fmaxf(rx[2], rx[3]));
    mmp[(size_t)(g * 64 + blockIdx.x) * 2] = mn;
    mmp[(size_t)(g * 64 + blockIdx.x) * 2 + 1] = mx;
  }
}

__global__ void k_minmax2(float* __restrict__ ws) {
  int g = blockIdx.x;
  int i = threadIdx.x;  // 64 threads
  float mn = ws[OFF_MMP + (size_t)(g * 64 + i) * 2];
  float mx = ws[OFF_MMP + (size_t)(g * 64 + i) * 2 + 1];
  for (int off = 32; off; off >>= 1) {
    mn = fminf(mn, __shfl_down(mn, off));
    mx = fmaxf(mx, __shfl_down(mx, off));
  }
  if (i == 0) {
    float denom = fmaxf(mx - mn, 1e-8f);
    float a = 1.f / denom;
    ws[OFF_AB + g * 2] = a;
    ws[OFF_AB + g * 2 + 1] = -mn * a;
  }
}

// lt_w column sums (two stage)
__global__ void k_colsum(const float* __restrict__ ltw, float* __restrict__ csp) {
  int e = blockIdx.x * 256 + threadIdx.x;
  int ks = blockIdx.y;
  if (e >= EA_) return;
  float s = 0.f;
  for (int n = ks * 125; n < (ks + 1) * 125; ++n) s += ltw[(size_t)n * EA_ + e];
  csp[(size_t)ks * EA_ + e] = s;
}
__global__ void k_colsum2(float* __restrict__ ws) {
  int e = blockIdx.x * 256 + threadIdx.x;
  if (e >= EA_) return;
  float s = 0.f;
  for (int ks = 0; ks < 16; ++ks) s += ws[OFF_CSP + (size_t)ks * EA_ + e];
  ws[OFF_CS + e] = s;
}

// lin epilogue: rng01 folded in -> RT[e][row144]
__global__ void k_epiLin(const float* __restrict__ part, const float* __restrict__ ltb,
                         float* __restrict__ ws, int ksplit) {
  int e = blockIdx.x * 256 + threadIdx.x;
  int row = blockIdx.y;
  if (e >= EA_) return;
  float s = 0.f;
  for (int ks = 0; ks < ksplit; ++ks) s += part[((size_t)(ks * R3_ + row)) * EA_ + e];
  int g = row / BT_;
  float a = ws[OFF_AB + g * 2], bb = ws[OFF_AB + g * 2 + 1];
  ws[OFF_RT + (size_t)e * R3_ + row] = fmaf(a, s, fmaf(bb, ws[OFF_CS + e], ltb[e]));
}

// qkv epilogue -> P[row144][9000]
__global__ void k_epiQkv(const float* __restrict__ part, const float* __restrict__ qkvb,
                         float* __restrict__ P, int ksplit) {
  int c = blockIdx.x * 256 + threadIdx.x;
  int row = blockIdx.y;
  if (c >= 3 * EA_) return;
  float s = 0.f;
  for (int ks = 0; ks < ksplit; ++ks) s += part[((size_t)(ks * R3_ + row)) * (3 * EA_) + c];
  P[(size_t)row * (3 * EA_) + c] = s + qkvb[c];
}

// attention core (tiny): one block per (mha, s, b, h)
__global__ void k_attn(const float* __restrict__ P, float* __restrict__ AoT) {
  int mha = blockIdx.y;
  int s_ = blockIdx.x / (B_ * H_);
  int rem = blockIdx.x % (B_ * H_);
  int b = rem / H_, h = rem % H_;
  const int pq[3] = {0, 1, 2}, pk[3] = {1, 2, 0}, pv[3] = {2, 0, 1};
  const float* qrow = P + ((size_t)(pq[mha] * BT_ + s_ * B_ + b)) * (3 * EA_) + h * HD_;
  __shared__ float sc[T_];
  __shared__ float red[4];
  for (int t = 0; t < T_; ++t) {
    const float* krow = P + ((size_t)(pk[mha] * BT_ + t * B_ + b)) * (3 * EA_) + EA_ + h * HD_;
    float p = 0.f;
    for (int d = threadIdx.x; d < HD_; d += 256) p = fmaf(qrow[d], krow[d], p);
    p = waveReduceSum(p);
    if ((threadIdx.x & 63) == 0) red[threadIdx.x >> 6] = p;
    __syncthreads();
    if (threadIdx.x == 0) sc[t] = (red[0] + red[1] + red[2] + red[3]) * 0.031622776601683794f;
    __syncthreads();
  }
  float a[T_];
  float m = sc[0];
#pragma unroll
  for (int t = 1; t < T_; ++t) m = fmaxf(m, sc[t]);
  float sum = 0.f;
#pragma unroll
  for (int t = 0; t < T_; ++t) { a[t] = expf(sc[t] - m); sum += a[t]; }
  float inv = 1.f / sum;
#pragma unroll
  for (int t = 0; t < T_; ++t) a[t] *= inv;
  int orow = mha * BT_ + s_ * B_ + b;
  for (int d = threadIdx.x; d < HD_; d += 256) {
    float o = 0.f;
#pragma unroll
    for (int t = 0; t < T_; ++t)
      o = fmaf(a[t], P[((size_t)(pv[mha] * BT_ + t * B_ + b)) * (3 * EA_) + 2 * EA_ + h * HD_ + d], o);
    AoT[(size_t)(h * HD_ + d) * R3_ + orow] = o;
  }
}

// attn-out epilogue -> OT[c][row144]
__global__ void k_epiAO(const float* __restrict__ part, const float* __restrict__ aob,
                        float* __restrict__ OT, int ksplit) {
  int c = blockIdx.x * 256 + threadIdx.x;
  int row = blockIdx.y;
  if (c >= EA_) return;
  float s = 0.f;
  for (int ks = 0; ks < ksplit; ++ks) s += part[((size_t)(ks * R3_ + row)) * EA_ + c];
  OT[(size_t)c * R3_ + row] = s + aob[c];
}

// ll epilogue: sum three mha branches -> out2_pre[b][t*N+n] (with BETA and 3*bias)
__global__ void k_epiLL(const float* __restrict__ part, const float* __restrict__ llb,
                        float* __restrict__ o2p, int ksplit) {
  int n = blockIdx.x * 256 + threadIdx.x;
  int row = blockIdx.y;  // t*B+b
  if (n >= N_) return;
  float s = 0.f;
  for (int g = 0; g < 3; ++g)
    for (int ks = 0; ks < ksplit; ++ks)
      s += part[((size_t)(ks * R3_ + g * BT_ + row)) * N_ + n];
  int t = row / B_, b = row % B_;
  o2p[(size_t)b * (T_ * N_) + t * N_ + n] = BETA_ * (s + 3.f * llb[n]);
}

// trunk projection outp[b,t,n]
__global__ void k_proj(const float* __restrict__ out4, const float* __restrict__ pw,
                       const float* __restrict__ pb, float* __restrict__ outp) {
  int i = blockIdx.x * 256 + threadIdx.x;
  if (i >= BTN_) return;
  int b = i / (T_ * N_);
  int t = (i / N_) % T_;
  int n = i % N_;
  float acc = pb[t];
  for (int t2 = 0; t2 < T_; ++t2) {
    const float* o = out4 + ((size_t)(b * T_ + t2) * N_ + n) * D_;
#pragma unroll
    for (int d = 0; d < D_; ++d) acc = fmaf(o[d], pw[(t2 * D_ + d) * T_ + t], acc);
  }
  outp[i] = acc;
}

// p2 (replicates the reshape(-1,T) quirk exactly)
__global__ void k_p2(const float* __restrict__ o2p, const float* __restrict__ p2w,
                     const float* __restrict__ p2b, float* __restrict__ o2f) {
  int i = blockIdx.x * 256 + threadIdx.x;
  if (i >= BTN_) return;
  int b = i / (T_ * N_);
  int t = (i / N_) % T_;
  int n = i % N_;
  float acc = p2b[t];
  const float* src = o2p + (size_t)b * (T_ * N_) + (size_t)n * T_;
#pragma unroll
  for (int c = 0; c < T_; ++c) acc = fmaf(src[c], p2w[c * T_ + t], acc);
  o2f[i] = acc;
}

__global__ void k_out3(const float* __restrict__ outp, const float* __restrict__ o2f,
                       float* __restrict__ dout) {
  int i = blockIdx.x * 256 + threadIdx.x;
  if (i < BTN_) dout[i] = outp[i] + o2f[i];
}

// row-normalize f1 (x10 for /0.1) and f2
__global__ void k_fnorm(const float* __restrict__ outp, const float* __restrict__ o2f,
                        float* __restrict__ g1, float* __restrict__ g2) {
  int r = blockIdx.x * 256 + threadIdx.x;
  if (r >= B_ * N_) return;
  int b = r / N_, n = r % N_;
  float v1[T_], v2[T_];
  float s1 = 0.f, s2 = 0.f;
#pragma unroll
  for (int t = 0; t < T_; ++t) {
    v1[t] = outp[(size_t)b * T_ * N_ + t * N_ + n];
    v2[t] = o2f[(size_t)b * T_ * N_ + t * N_ + n];
    s1 = fmaf(v1[t], v1[t], s1);
    s2 = fmaf(v2[t], v2[t], s2);
  }
  float n1 = fmaxf(sqrtf(s1), 1e-12f), n2 = fmaxf(sqrtf(s2), 1e-12f);
  float i1 = 10.f / n1, i2 = 1.f / n2;
#pragma unroll
  for (int t = 0; t < T_; ++t) {
    g1[(size_t)r * T_ + t] = v1[t] * i1;
    g2[(size_t)r * T_ + t] = v2[t] * i2;
  }
}

// per-row logsumexp + diagonal of sim.
// 16 rows per block x 16 threads per row; one accumulator per thread (no spill).
__global__ __launch_bounds__(256) void k_lse(const float* __restrict__ g1,
                                             const float* __restrict__ g2,
                                             float* __restrict__ li) {
  int r = threadIdx.x >> 4;   // 0..15 row within block
  int k = threadIdx.x & 15;   // 0..15 j-phase
  int row = blockIdx.x * 16 + r;
  const float4* qp = (const float4*)(g1 + (size_t)row * T_);
  float4 qa = qp[0], qb = qp[1], qc = qp[2];
  float sm = 0.f, sd = 0.f;
  for (int j = k; j < B_ * N_; j += 16) {
    const float4* p = (const float4*)(g2 + (size_t)j * T_);
    float4 A = p[0], Bv = p[1], C = p[2];
    float s = qa.x * A.x;
    s = fmaf(qa.y, A.y, s);  s = fmaf(qa.z, A.z, s);  s = fmaf(qa.w, A.w, s);
    s = fmaf(qb.x, Bv.x, s); s = fmaf(qb.y, Bv.y, s); s = fmaf(qb.z, Bv.z, s);
    s = fmaf(qb.w, Bv.w, s); s = fmaf(qc.x, C.x, s);  s = fmaf(qc.y, C.y, s);
    s = fmaf(qc.z, C.z, s);  s = fmaf(qc.w, C.w, s);
    sm += __expf(s);
    if (j == row) sd = s;
  }
#pragma unroll
  for (int off = 8; off; off >>= 1) {
    sm += __shfl_xor(sm, off);
    sd += __shfl_xor(sd, off);
  }
  if (k == 0) li[row] = sd - logf(sm);
}

__global__ void k_final(const float* __restrict__ li, const float* __restrict__ ws,
                        float* __restrict__ dout) {
  float s = 0.f;
  for (int i = threadIdx.x; i < B_ * N_; i += 256) s += li[i];
  __shared__ float red[4];
  s = waveReduceSum(s);
  if ((threadIdx.x & 63) == 0) red[threadIdx.x >> 6] = s;
  __syncthreads();
  if (threadIdx.x == 0) {
    float closs = -(red[0] + red[1] + red[2] + red[3]) * (1.f / (B_ * N_));
    dout[BTN_] = ws[OFF_BAL];
    dout[BTN_ + 1] = CW_ * closs;
  }
}

// ---------------------------------------------------------------------------
extern "C" void kernel_launch(void* const* d_in, const int* in_sizes, int n_in,
                              void* d_out, int out_size, void* d_ws, size_t ws_size,
                              hipStream_t stream) {
  const float* x    = (const float*)d_in[0];
  const float* velo = (const float*)d_in[1];
  const float* adj  = (const float*)d_in[2];
  const float* lapd = (const float*)d_in[3];
  const float* laph = (const float*)d_in[4];
  const float* sw   = (const float*)d_in[5];
  const float* sb   = (const float*)d_in[6];
  const float* gw   = (const float*)d_in[7];
  const float* ew1  = (const float*)d_in[8];
  const float* eb1  = (const float*)d_in[9];
  const float* ew2  = (const float*)d_in[10];
  const float* eb2  = (const float*)d_in[11];
  const float* pw   = (const float*)d_in[12];
  const float* pb   = (const float*)d_in[13];
  const float* ltw  = (const float*)d_in[14];
  const float* ltb  = (const float*)d_in[15];
  const float* qkvw = (const float*)d_in[16];
  const float* qkvb = (const float*)d_in[17];
  const float* aow  = (const float*)d_in[18];
  const float* aob  = (const float*)d_in[19];
  const float* llw  = (const float*)d_in[20];
  const float* llb  = (const float*)d_in[21];
  const float* p2w  = (const float*)d_in[22];
  const float* p2b  = (const float*)d_in[23];
  float* ws = (float*)d_ws;
  float* dout = (float*)d_out;
  const float* v0 = velo;  // velo[0,0,:]
  float* part = ws + OFF_PART;
  dim3 b256(256);

  k_init<<<dim3(1), dim3(64), 0, stream>>>(ws);
  k_start<<<dim3((BTN_ * D_ + 255) / 256), b256, 0, stream>>>(x, sw, sb, ws + OFF_OUT4);

  for (int l = 0; l < L_; ++l) {
    k_feat<<<dim3(B_ * D_), b256, 0, stream>>>(ws + OFF_OUT4, ws + OFF_FEAT);
    k_gate<<<dim3(1), dim3(64), 0, stream>>>(ws + OFF_FEAT, gw, ws, l);
    k_expert<<<dim3((T_ * N_ + 255) / 256, B_), b256, 0, stream>>>(ws + OFF_OUT4, ew1, eb1, ew2, eb2, ws, l);
  }

  k_wavelet<<<dim3((BTN_ + 255) / 256), b256, 0, stream>>>(x, velo, ws + OFF_LOWT, ws + OFF_HVT);
  k_rowsum<<<dim3(2 * BT_), b256, 0, stream>>>(ws + OFF_LOWT, ws + OFF_HVT, ws);
  k_S<<<dim3(N_), b256, 0, stream>>>(adj, v0, ws + OFF_S);
  k_stats<<<dim3(512), b256, 0, stream>>>(lapd, ws + OFF_STP);
  k_stats2<<<dim3(1), b256, 0, stream>>>(ws + OFF_STP, ws + OFF_STAT);
  k_stats<<<dim3(512), b256, 0, stream>>>(laph, ws + OFF_STP + 1024);
  k_stats2<<<dim3(1), b256, 0, stream>>>(ws + OFF_STP + 1024, ws + OFF_STAT + 2);
  k_nsstats<<<dim3(512), b256, 0, stream>>>(adj, v0, ws + OFF_S, ws + OFF_STP + 2048);
  k_stats2<<<dim3(1), b256, 0, stream>>>(ws + OFF_STP + 2048, ws + OFF_STAT + 4);

  // r1 / r2 / r3 with fused normalization (split-K 50, kchunk 40 = 5 groups of 8)
  k_gemm48<<<dim3(8, RKS_, 1), b256, 0, stream>>>(ws + OFF_LOWT, BT_, BT_, lapd, part, N_, N_, RKC_);
  k_epiR<<<dim3(8, 48), b256, 0, stream>>>(part, ws, RKS_, 0, 0, OFF_RSL);
  k_gemmNS<<<dim3(8, RKS_), b256, 0, stream>>>(ws + OFF_HVT, adj, v0, ws + OFF_S, part, RKC_);
  k_epiR<<<dim3(8, 48), b256, 0, stream>>>(part, ws, RKS_, 1, 4, OFF_RSH);
  k_gemm48<<<dim3(8, RKS_, 1), b256, 0, stream>>>(ws + OFF_LOWT, BT_, BT_, laph, part, N_, N_, RKC_);
  k_epiR<<<dim3(8, 48), b256, 0, stream>>>(part, ws, RKS_, 2, 2, OFF_RSL);

  k_minmax<<<dim3(64, 3), b256, 0, stream>>>(ws + OFF_ALIN, ws + OFF_MMP);
  k_minmax2<<<dim3(3), dim3(64), 0, stream>>>(ws);
  k_colsum<<<dim3(12, 16), b256, 0, stream>>>(ltw, ws + OFF_CSP);
  k_colsum2<<<dim3(12), b256, 0, stream>>>(ws);

  // lin: [144,2000] @ lt_w  (3 row-groups of 48)
  k_gemm48<<<dim3(12, 16, 3), b256, 0, stream>>>(ws + OFF_ALIN, R3_, R3_, ltw, part, N_, EA_, 125);
  k_epiLin<<<dim3(12, 144), b256, 0, stream>>>(part, ltb, ws, 16);

  // qkv: [144,3000] @ qkv_w[3000,9000]
  int qks = (ws_size >= (OFF_PART + (size_t)8 * R3_ * 3 * EA_) * 4) ? 8 : 4;
  k_gemm48<<<dim3(36, qks, 3), b256, 0, stream>>>(ws + OFF_RT, R3_, R3_, qkvw, part, EA_, 3 * EA_, (EA_ + qks - 1) / qks);
  k_epiQkv<<<dim3(36, 144), b256, 0, stream>>>(part, qkvb, ws + OFF_P, qks);

  // attention (3 mha in grid.y)
  k_attn<<<dim3(T_ * B_ * H_, 3), b256, 0, stream>>>(ws + OFF_P, ws + OFF_AOT);

  // attn out projection
  k_gemm48<<<dim3(12, 16, 3), b256, 0, stream>>>(ws + OFF_AOT, R3_, R3_, aow, part, EA_, EA_, 188);
  k_epiAO<<<dim3(12, 144), b256, 0, stream>>>(part, aob, ws + OFF_OT, 16);

  // ll (back) projection + branch sum
  k_gemm48<<<dim3(8, 16, 3), b256, 0, stream>>>(ws + OFF_OT, R3_, R3_, llw, part, EA_, N_, 188);
  k_epiLL<<<dim3(8, 48), b256, 0, stream>>>(part, llb, ws + OFF_O2P, 16);

  k_proj<<<dim3((BTN_ + 255) / 256), b256, 0, stream>>>(ws + OFF_OUT4, pw, pb, ws + OFF_OUTP);
  k_p2<<<dim3((BTN_ + 255) / 256), b256, 0, stream>>>(ws + OFF_O2P, p2w, p2b, ws + OFF_O2F);
  k_out3<<<dim3((BTN_ + 255) / 256), b256, 0, stream>>>(ws + OFF_OUTP, ws + OFF_O2F, dout);

  k_fnorm<<<dim3((B_ * N_ + 255) / 256), b256, 0, stream>>>(ws + OFF_OUTP, ws + OFF_O2F, ws + OFF_G1, ws + OFF_G2);
  k_lse<<<dim3(B_ * N_ / 16), b256, 0, stream>>>(ws + OFF_G1, ws + OFF_G2, ws + OFF_LI);
  k_final<<<dim3(1), b256, 0, stream>>>(ws + OFF_LI, ws, dout);
}